// Round 2
// baseline (1234.637 us; speedup 1.0000x reference)
//
#include <hip/hip_runtime.h>
#include <hip/hip_bf16.h>

#define THREADS 512
#define WPB 8
#define NWIN 16384
#define NBLK (NWIN / WPB)

typedef short bf16x8 __attribute__((ext_vector_type(8)));
typedef float f32x4 __attribute__((ext_vector_type(4)));

// ---- LDS pool (ushort units). Deliberate over-reads of padded MFMA rows land
// in the next region (finite bf16 values, results discarded) — all in-pool. ----
#define XAP 136   // xa: [49][136] bf16  (x staging, then attn-out)
#define QKP 264   // qk: [49][264] bf16  (cols 0..255 = q|k channels)
#define VTP 72    // vt: [128][72] bf16  (rows = dims, cols = tokens)
#define PSP 40    // ps: per-wave [16][40] bf16 P staging
#define MSP 68    // maskF: [49][68] f32 (pre-scaled by log2e)

#define XA_OFF 0
#define QK_OFF 6664
#define VT_OFF 19600
#define PS_OFF 28816
#define MS_OFF 33936            // ushort offset; cast to float* (byte 67872, 16B aligned)
#define POOL_USHORTS 40600      // 81,200 bytes -> 81,408 alloc -> 2 blocks/CU

#define LOG2E 1.4426950408889634f
#define SCALE_Q 0.17677669529663689f   // 32^-0.5

static __device__ __forceinline__ unsigned short f2bf(float x) {
    union { __hip_bfloat16 b; unsigned short u; } c;
    c.b = __float2bfloat16(x);
    return c.u;
}
static __device__ __forceinline__ unsigned pack2bf(float lo, float hi) {
    return (unsigned)f2bf(lo) | ((unsigned)f2bf(hi) << 16);
}
static __device__ __forceinline__ ushort4 cvt4(float4 v) {
    ushort4 u; u.x = f2bf(v.x); u.y = f2bf(v.y); u.z = f2bf(v.z); u.w = f2bf(v.w);
    return u;
}

__global__ __launch_bounds__(THREADS, 4)
void winattn_kernel(const float* __restrict__ x, const float* __restrict__ mask,
                    const float* __restrict__ qkv_w, const float* __restrict__ qkv_b,
                    const float* __restrict__ proj_w, const float* __restrict__ proj_b,
                    const float* __restrict__ bias_table, const int* __restrict__ rel_index,
                    float* __restrict__ out)
{
    __shared__ __align__(16) unsigned short pool[POOL_USHORTS];
    float* maskF = (float*)&pool[MS_OFF];

    const int tid  = threadIdx.x;
    const int wave = tid >> 6;
    const int lane = tid & 63;
    const int lg   = lane >> 4;
    const int l16  = lane & 15;
    const int h    = wave >> 1;      // head
    const int mh   = wave & 1;       // q-half (32 tokens)

    // ---------------- persistent per-block state ----------------
    // qkv_w fragments: wave owns output channels [48*wave, 48*wave+48), 3 tiles.
    // Fragment: lane l16 = channel-in-tile, dims = ks*32 + lg*8. q-channels folded
    // with SCALE*LOG2E.
    bf16x8 wB[3][4];
#pragma unroll
    for (int nt = 0; nt < 3; ++nt) {
        const int chB = wave * 48 + nt * 16;
        const float s = (chB < 128) ? (SCALE_Q * LOG2E) : 1.0f;
        const float* wp = qkv_w + (size_t)(chB + l16) * 128;
#pragma unroll
        for (int ks = 0; ks < 4; ++ks) {
            const float* p = wp + ks * 32 + lg * 8;
            bf16x8 f;
#pragma unroll
            for (int j = 0; j < 8; ++j) f[j] = (short)f2bf(p[j] * s);
            wB[nt][ks] = f;
        }
    }
    // relative-position bias, packed bf16 pairs, pre-scaled by LOG2E.
    // lane needs: qt = mh*32+nt*16+l16 (nt 0..1), kt = mt*16+lg*4+r (mt 0..3).
    unsigned biasP[2][4][2];
#pragma unroll
    for (int nt = 0; nt < 2; ++nt) {
        int qt = mh * 32 + nt * 16 + l16; if (qt > 48) qt = 48;
#pragma unroll
        for (int mt = 0; mt < 4; ++mt) {
#pragma unroll
            for (int w2 = 0; w2 < 2; ++w2) {
                float b[2];
#pragma unroll
                for (int r = 0; r < 2; ++r) {
                    int kt = mt * 16 + lg * 4 + w2 * 2 + r; if (kt > 48) kt = 48;
                    const int idx = rel_index[qt * 49 + kt];
                    b[r] = bias_table[idx * 4 + h] * LOG2E;
                }
                biasP[nt][mt][w2] = pack2bf(b[0], b[1]);
            }
        }
    }
    const float4 pb = *(const float4*)(proj_b + wave * 16 + lg * 4);

    const int win0 = blockIdx.x * WPB;

    // ---------------- prologue: zero qk+vt, stage window 0 ----------------
    {
        unsigned* p32 = (unsigned*)pool;
        for (int i = QK_OFF / 2 + tid; i < QK_OFF / 2 + (12936 + 9216) / 2; i += THREADS)
            p32[i] = 0;
    }
#pragma unroll
    for (int it = 0; it < 4; ++it) {
        const int e = it * 2048 + tid * 4;
        if (e < 6272) {
            float4 v = *(const float4*)(x + (size_t)win0 * 6272 + e);
            *(ushort4*)&pool[XA_OFF + (e >> 7) * XAP + (e & 127)] = cvt4(v);
        }
    }
    {
        const float* mp0 = mask + (size_t)(win0 & 1023) * 2401;
        for (int e = tid; e < 2401; e += THREADS)
            maskF[(e / 49) * MSP + (e % 49)] = mp0[e] * LOG2E;
    }
    __syncthreads();

    for (int w = 0; w < WPB; ++w) {
        const int win = win0 + w;
        const bool pf = (w + 1 < WPB);

        // -------- issue prefetch of next window (x, mask) --------
        float4 xr[4];
        float  mr[5];
        if (pf) {
            const float* xp1 = x + (size_t)(win + 1) * 6272;
#pragma unroll
            for (int it = 0; it < 4; ++it) {
                const int e = it * 2048 + tid * 4;
                if (e < 6272) xr[it] = *(const float4*)(xp1 + e);
            }
            const float* mp1 = mask + (size_t)((win + 1) & 1023) * 2401;
#pragma unroll
            for (int it = 0; it < 5; ++it) {
                const int e = it * THREADS + tid;
                if (e < 2401) mr[it] = mp1[e];
            }
        }

        // -------- QKV GEMM (mt-major; per-tile operand orientation) --------
        // q/k tiles: mfma(W, x) -> col=token, row-quad=channels -> ushort4 row write
        // v  tiles: mfma(x, W) -> col=channel, row-quad=tokens  -> ushort4 into vt
        float4 qb4[3];
#pragma unroll
        for (int nt = 0; nt < 3; ++nt) {
            const int chB = wave * 48 + nt * 16;
            if (chB < 256) {
                float4 b = *(const float4*)(qkv_b + chB + lg * 4);
                if (chB < 128) { b.x *= SCALE_Q * LOG2E; b.y *= SCALE_Q * LOG2E;
                                 b.z *= SCALE_Q * LOG2E; b.w *= SCALE_Q * LOG2E; }
                qb4[nt] = b;
            } else {
                qb4[nt].x = qkv_b[chB + l16];
            }
        }
#pragma unroll
        for (int mt = 0; mt < 4; ++mt) {
            bf16x8 xf[4];
#pragma unroll
            for (int ks = 0; ks < 4; ++ks)
                xf[ks] = *(const bf16x8*)&pool[XA_OFF + (mt * 16 + l16) * XAP + ks * 32 + lg * 8];
#pragma unroll
            for (int nt = 0; nt < 3; ++nt) {
                const int chB = wave * 48 + nt * 16;
                f32x4 acc = (f32x4){0.f, 0.f, 0.f, 0.f};
                if (chB < 256) {
#pragma unroll
                    for (int ks = 0; ks < 4; ++ks)
                        acc = __builtin_amdgcn_mfma_f32_16x16x32_bf16(wB[nt][ks], xf[ks], acc, 0, 0, 0);
                    const int tok = mt * 16 + l16;
                    if (tok < 49) {
                        float4 v; v.x = acc[0] + qb4[nt].x; v.y = acc[1] + qb4[nt].y;
                        v.z = acc[2] + qb4[nt].z; v.w = acc[3] + qb4[nt].w;
                        *(ushort4*)&pool[QK_OFF + tok * QKP + chB + lg * 4] = cvt4(v);
                    }
                } else {
#pragma unroll
                    for (int ks = 0; ks < 4; ++ks)
                        acc = __builtin_amdgcn_mfma_f32_16x16x32_bf16(xf[ks], wB[nt][ks], acc, 0, 0, 0);
                    const float vb = qb4[nt].x;
                    float4 v; v.x = acc[0] + vb; v.y = acc[1] + vb;
                    v.z = acc[2] + vb; v.w = acc[3] + vb;
                    *(ushort4*)&pool[VT_OFF + (chB - 256 + l16) * VTP + mt * 16 + lg * 4] = cvt4(v);
                }
            }
        }
        __syncthreads();   // BAR1: q/k/v visible; xa free (consumed)

        // convert prefetched x to bf16 early (frees f32 regs)
        ushort4 xb[4];
        if (pf) {
#pragma unroll
            for (int it = 0; it < 4; ++it) xb[it] = cvt4(xr[it]);
        }

        // -------- attention: S' = K * Q^T (softmax over in-lane kt) --------
        bf16x8 ak[4];
#pragma unroll
        for (int mt = 0; mt < 4; ++mt)
            ak[mt] = *(const bf16x8*)&pool[QK_OFF + (mt * 16 + l16) * QKP + 128 + h * 32 + lg * 8];

        float inv[2];
        unsigned pk[2][4][2];
#pragma unroll
        for (int nt = 0; nt < 2; ++nt) {
            const bf16x8 bq = *(const bf16x8*)&pool[QK_OFF + (mh * 32 + nt * 16 + l16) * QKP + h * 32 + lg * 8];
            f32x4 S[4];
#pragma unroll
            for (int mt = 0; mt < 4; ++mt)
                S[mt] = __builtin_amdgcn_mfma_f32_16x16x32_bf16(ak[mt], bq, (f32x4){0.f,0.f,0.f,0.f}, 0, 0, 0);

            const int qt = mh * 32 + nt * 16 + l16;
            const bool qok = (qt < 49);
            const int qrow = qok ? qt : 48;
            float lv[4][4];
#pragma unroll
            for (int mt = 0; mt < 4; ++mt) {
                const float4 mm = *(const float4*)&maskF[qrow * MSP + mt * 16 + lg * 4];
                const unsigned b0 = biasP[nt][mt][0], b1 = biasP[nt][mt][1];
                const float bb0 = __uint_as_float(b0 << 16);
                const float bb1 = __uint_as_float(b0 & 0xffff0000u);
                const float bb2 = __uint_as_float(b1 << 16);
                const float bb3 = __uint_as_float(b1 & 0xffff0000u);
                const int kt0 = mt * 16 + lg * 4;
                lv[mt][0] = (qok && kt0 + 0 < 49) ? (S[mt][0] + bb0 + mm.x) : -1e30f;
                lv[mt][1] = (qok && kt0 + 1 < 49) ? (S[mt][1] + bb1 + mm.y) : -1e30f;
                lv[mt][2] = (qok && kt0 + 2 < 49) ? (S[mt][2] + bb2 + mm.z) : -1e30f;
                lv[mt][3] = (qok && kt0 + 3 < 49) ? (S[mt][3] + bb3 + mm.w) : -1e30f;
            }
            float mx = lv[0][0];
#pragma unroll
            for (int mt = 0; mt < 4; ++mt)
#pragma unroll
                for (int r = 0; r < 4; ++r) mx = fmaxf(mx, lv[mt][r]);
            mx = fmaxf(mx, __shfl_xor(mx, 16));
            mx = fmaxf(mx, __shfl_xor(mx, 32));
            float sum = 0.f;
#pragma unroll
            for (int mt = 0; mt < 4; ++mt)
#pragma unroll
                for (int r = 0; r < 4; ++r) {
                    const float p = exp2f(lv[mt][r] - mx);
                    lv[mt][r] = p;
                    sum += p;
                }
            sum += __shfl_xor(sum, 16);
            sum += __shfl_xor(sum, 32);
            inv[nt] = 1.0f / sum;
#pragma unroll
            for (int mt = 0; mt < 4; ++mt) {
                pk[nt][mt][0] = pack2bf(lv[mt][0], lv[mt][1]);
                pk[nt][mt][1] = pack2bf(lv[mt][2], lv[mt][3]);
            }
        }

        // -------- PV: O' = V^T * P^T (per-wave LDS P round-trips) --------
        f32x4 O[2][2];   // [dim-tile][tok-tile]
#pragma unroll
        for (int i = 0; i < 2; ++i)
#pragma unroll
            for (int j = 0; j < 2; ++j) O[i][j] = (f32x4){0.f, 0.f, 0.f, 0.f};
        const int psb = PS_OFF + wave * 16 * PSP;
#pragma unroll
        for (int kh = 0; kh < 2; ++kh) {
            bf16x8 bv[2];
#pragma unroll
            for (int i = 0; i < 2; ++i)
                bv[i] = *(const bf16x8*)&pool[VT_OFF + (h * 32 + i * 16 + l16) * VTP + kh * 32 + lg * 8];
#pragma unroll
            for (int j = 0; j < 2; ++j) {
                uint2 t0, t1;
                t0.x = pk[j][2 * kh + 0][0]; t0.y = pk[j][2 * kh + 0][1];
                t1.x = pk[j][2 * kh + 1][0]; t1.y = pk[j][2 * kh + 1][1];
                *(uint2*)&pool[psb + l16 * PSP + lg * 4]      = t0;
                *(uint2*)&pool[psb + l16 * PSP + 16 + lg * 4] = t1;
                asm volatile("s_waitcnt lgkmcnt(0)" ::: "memory");
                const bf16x8 pa = *(const bf16x8*)&pool[psb + l16 * PSP + lg * 8];
#pragma unroll
                for (int i = 0; i < 2; ++i)
                    O[i][j] = __builtin_amdgcn_mfma_f32_16x16x32_bf16(bv[i], pa, O[i][j], 0, 0, 0);
            }
        }
        // attn-out -> xa (row write along dims), fold 1/sum
#pragma unroll
        for (int j = 0; j < 2; ++j) {
            const int tok = mh * 32 + j * 16 + l16;
            if (tok < 49) {
#pragma unroll
                for (int i = 0; i < 2; ++i) {
                    float4 v;
                    v.x = O[i][j][0] * inv[j]; v.y = O[i][j][1] * inv[j];
                    v.z = O[i][j][2] * inv[j]; v.w = O[i][j][3] * inv[j];
                    *(ushort4*)&pool[XA_OFF + tok * XAP + h * 32 + i * 16 + lg * 4] = cvt4(v);
                }
            }
        }
        __syncthreads();   // BAR2: attn-out visible; maskF free

        // store prefetched mask (readers finished at BAR2)
        if (pf) {
#pragma unroll
            for (int it = 0; it < 5; ++it) {
                const int e = it * THREADS + tid;
                if (e < 2401) maskF[(e / 49) * MSP + (e % 49)] = mr[it] * LOG2E;
            }
        }

        // -------- proj: out^T = proj_w * aout^T (coalesced float4 store) --------
        bf16x8 wp[4];
        {
            const float* pwr = proj_w + (size_t)(wave * 16 + l16) * 128;
#pragma unroll
            for (int ks = 0; ks < 4; ++ks) {
                const float* p = pwr + ks * 32 + lg * 8;
                bf16x8 f;
#pragma unroll
                for (int j = 0; j < 8; ++j) f[j] = (short)f2bf(p[j]);
                wp[ks] = f;
            }
        }
#pragma unroll
        for (int nt4 = 0; nt4 < 4; ++nt4) {
            f32x4 pc = (f32x4){0.f, 0.f, 0.f, 0.f};
#pragma unroll
            for (int ks = 0; ks < 4; ++ks) {
                const bf16x8 bfr = *(const bf16x8*)&pool[XA_OFF + (nt4 * 16 + l16) * XAP + ks * 32 + lg * 8];
                pc = __builtin_amdgcn_mfma_f32_16x16x32_bf16(wp[ks], bfr, pc, 0, 0, 0);
            }
            const int tok = nt4 * 16 + l16;
            if (tok < 49) {
                float4 o;
                o.x = pc[0] + pb.x; o.y = pc[1] + pb.y;
                o.z = pc[2] + pb.z; o.w = pc[3] + pb.w;
                *(float4*)(out + ((size_t)win * 49 + tok) * 128 + wave * 16 + lg * 4) = o;
            }
        }
        __syncthreads();   // BAR3: proj's xa reads done

        if (pf) {
#pragma unroll
            for (int it = 0; it < 4; ++it) {
                const int e = it * 2048 + tid * 4;
                if (e < 6272)
                    *(ushort4*)&pool[XA_OFF + (e >> 7) * XAP + (e & 127)] = xb[it];
            }
        }
        __syncthreads();   // BAR4: next window's x staged
    }
}

extern "C" void kernel_launch(void* const* d_in, const int* in_sizes, int n_in,
                              void* d_out, int out_size, void* d_ws, size_t ws_size,
                              hipStream_t stream) {
    const float* x          = (const float*)d_in[0];
    const float* mask       = (const float*)d_in[1];
    const float* qkv_w      = (const float*)d_in[2];
    const float* qkv_b      = (const float*)d_in[3];
    const float* proj_w     = (const float*)d_in[4];
    const float* proj_b     = (const float*)d_in[5];
    const float* bias_table = (const float*)d_in[6];
    const int*   rel_index  = (const int*)d_in[7];
    float* out = (float*)d_out;
    (void)in_sizes; (void)n_in; (void)d_ws; (void)ws_size; (void)out_size;

    winattn_kernel<<<dim3(NBLK), dim3(THREADS), 0, stream>>>(
        x, mask, qkv_w, qkv_b, proj_w, proj_b, bias_table, rel_index, out);
}

// Round 3
// 743.019 us; speedup vs baseline: 1.6616x; 1.6616x over previous
//
#include <hip/hip_runtime.h>
#include <hip/hip_bf16.h>

#define THREADS 512
#define WPB 8
#define NWIN 16384
#define NBLK (NWIN / WPB)

typedef short bf16x8 __attribute__((ext_vector_type(8)));
typedef float f32x4 __attribute__((ext_vector_type(4)));

// ---- LDS pool (ushort units). Deliberate over-reads of padded MFMA rows land
// in the next region (finite bf16 values, results discarded) — all in-pool. ----
#define XAP 136   // xa: [49][136] bf16  (x staging, then attn-out)
#define QKP 264   // qk: [49][264] bf16  (cols 0..255 = q|k channels)
#define VTP 72    // vt: [128][72] bf16  (rows = dims, cols = tokens)
#define PSP 40    // ps: per-wave [16][40] bf16 P staging
#define MSP 68    // maskF: [49][68] f32 (pre-scaled by log2e)

#define XA_OFF 0
#define QK_OFF 6664
#define VT_OFF 19600
#define PS_OFF 28816
#define MS_OFF 33936            // ushort offset; cast to float* (byte 67872, 16B aligned)
#define POOL_USHORTS 40600      // 81,200 bytes -> 81,408 alloc -> 2 blocks/CU

#define LOG2E 1.4426950408889634f
#define SCALE_Q 0.17677669529663689f   // 32^-0.5

// ws layout: wq = 96 fragment-groups (wave*3+nt)*4+ks, 64 lanes, 8 bf16 each
//            wp = 32 fragment-groups (wave*4+ks),      64 lanes, 8 bf16 each
#define WQ_USHORTS (96 * 64 * 8)
#define WP_USHORTS (32 * 64 * 8)

static __device__ __forceinline__ unsigned short f2bf(float x) {
    union { __hip_bfloat16 b; unsigned short u; } c;
    c.b = __float2bfloat16(x);
    return c.u;
}
static __device__ __forceinline__ unsigned pack2bf(float lo, float hi) {
    return (unsigned)f2bf(lo) | ((unsigned)f2bf(hi) << 16);
}
static __device__ __forceinline__ ushort4 cvt4(float4 v) {
    ushort4 u; u.x = f2bf(v.x); u.y = f2bf(v.y); u.z = f2bf(v.z); u.w = f2bf(v.w);
    return u;
}

// ---------------- prep: fp32 weights -> pre-swizzled bf16 fragments in ws ----------------
__global__ __launch_bounds__(512)
void prep_weights(const float* __restrict__ qkv_w, const float* __restrict__ proj_w,
                  unsigned short* __restrict__ wq, unsigned short* __restrict__ wp)
{
    const int t = blockIdx.x * 512 + threadIdx.x;
    if (t < 96 * 64) {
        const int lane = t & 63, g = t >> 6;
        const int l16 = lane & 15, lg = lane >> 4;
        const int ks = g & 3, wn = g >> 2;                 // wn = wave*3+nt
        const int ch = wn * 16 + l16;                      // qkv output channel
        const float s = (ch < 128) ? (SCALE_Q * LOG2E) : 1.0f;
        const float* p = qkv_w + (size_t)ch * 128 + ks * 32 + lg * 8;
        bf16x8 f;
#pragma unroll
        for (int j = 0; j < 8; ++j) f[j] = (short)f2bf(p[j] * s);
        *(bf16x8*)&wq[(size_t)t * 8] = f;
    } else if (t < 96 * 64 + 32 * 64) {
        const int t2 = t - 96 * 64;
        const int lane = t2 & 63, g = t2 >> 6;             // g = wave*4+ks
        const int l16 = lane & 15, lg = lane >> 4;
        const int ks = g & 3, wv = g >> 2;
        const float* p = proj_w + (size_t)(wv * 16 + l16) * 128 + ks * 32 + lg * 8;
        bf16x8 f;
#pragma unroll
        for (int j = 0; j < 8; ++j) f[j] = (short)f2bf(p[j]);
        *(bf16x8*)&wp[(size_t)t2 * 8] = f;
    }
}

__global__ __launch_bounds__(THREADS, 4)
void winattn_kernel(const float* __restrict__ x, const float* __restrict__ mask,
                    const unsigned short* __restrict__ wq, const unsigned short* __restrict__ wpr,
                    const float* __restrict__ qkv_b, const float* __restrict__ proj_b,
                    const float* __restrict__ bias_table, const int* __restrict__ rel_index,
                    float* __restrict__ out)
{
    __shared__ __align__(16) unsigned short pool[POOL_USHORTS];
    float* maskF = (float*)&pool[MS_OFF];

    const int tid  = threadIdx.x;
    const int wave = tid >> 6;
    const int lane = tid & 63;
    const int lg   = lane >> 4;
    const int l16  = lane & 15;
    const int h    = wave >> 1;      // head
    const int mh   = wave & 1;       // q-half (32 tokens)

    // ---------------- persistent per-block state (20 VGPRs) ----------------
    // relative-position bias, packed bf16 pairs, pre-scaled by LOG2E.
    unsigned biasP[2][4][2];
#pragma unroll
    for (int nt = 0; nt < 2; ++nt) {
        int qt = mh * 32 + nt * 16 + l16; if (qt > 48) qt = 48;
#pragma unroll
        for (int mt = 0; mt < 4; ++mt) {
#pragma unroll
            for (int w2 = 0; w2 < 2; ++w2) {
                float b[2];
#pragma unroll
                for (int r = 0; r < 2; ++r) {
                    int kt = mt * 16 + lg * 4 + w2 * 2 + r; if (kt > 48) kt = 48;
                    const int idx = rel_index[qt * 49 + kt];
                    b[r] = bias_table[idx * 4 + h] * LOG2E;
                }
                biasP[nt][mt][w2] = pack2bf(b[0], b[1]);
            }
        }
    }
    const float4 pb = *(const float4*)(proj_b + wave * 16 + lg * 4);

    const int win0 = blockIdx.x * WPB;

    // ---------------- prologue: zero qk+vt, stage window 0 ----------------
    {
        unsigned* p32 = (unsigned*)pool;
        for (int i = QK_OFF / 2 + tid; i < QK_OFF / 2 + (12936 + 9216) / 2; i += THREADS)
            p32[i] = 0;
    }
#pragma unroll
    for (int it = 0; it < 4; ++it) {
        const int e = it * 2048 + tid * 4;
        if (e < 6272) {
            float4 v = *(const float4*)(x + (size_t)win0 * 6272 + e);
            *(ushort4*)&pool[XA_OFF + (e >> 7) * XAP + (e & 127)] = cvt4(v);
        }
    }
    {
        const float* mp0 = mask + (size_t)(win0 & 1023) * 2401;
        for (int e = tid; e < 2401; e += THREADS)
            maskF[(e / 49) * MSP + (e % 49)] = mp0[e] * LOG2E;
    }
    __syncthreads();

    for (int w = 0; w < WPB; ++w) {
        const int win = win0 + w;
        const bool pf = (w + 1 < WPB);

        // -------- QKV GEMM (mt-major; per-tile operand orientation) --------
        // Weight fragments reloaded from L2 each window (pointer laundered so
        // LICM can't hoist them into 48 persistent VGPRs).
        bf16x8 wB[3][4];
        {
            uintptr_t wqu = (uintptr_t)wq;
            asm volatile("" : "+s"(wqu));
            const unsigned short* wqx = (const unsigned short*)wqu;
#pragma unroll
            for (int nt = 0; nt < 3; ++nt)
#pragma unroll
                for (int ks = 0; ks < 4; ++ks)
                    wB[nt][ks] = *(const bf16x8*)&wqx[(size_t)(((wave * 3 + nt) * 4 + ks) * 64 + lane) * 8];
        }
        float4 qb4[3];
#pragma unroll
        for (int nt = 0; nt < 3; ++nt) {
            const int chB = wave * 48 + nt * 16;
            if (chB < 256) {
                float4 b = *(const float4*)(qkv_b + chB + lg * 4);
                if (chB < 128) { b.x *= SCALE_Q * LOG2E; b.y *= SCALE_Q * LOG2E;
                                 b.z *= SCALE_Q * LOG2E; b.w *= SCALE_Q * LOG2E; }
                qb4[nt] = b;
            } else {
                qb4[nt].x = qkv_b[chB + l16];
            }
        }
#pragma unroll
        for (int mt = 0; mt < 4; ++mt) {
            bf16x8 xf[4];
#pragma unroll
            for (int ks = 0; ks < 4; ++ks)
                xf[ks] = *(const bf16x8*)&pool[XA_OFF + (mt * 16 + l16) * XAP + ks * 32 + lg * 8];
#pragma unroll
            for (int nt = 0; nt < 3; ++nt) {
                const int chB = wave * 48 + nt * 16;
                f32x4 acc = (f32x4){0.f, 0.f, 0.f, 0.f};
                if (chB < 256) {
#pragma unroll
                    for (int ks = 0; ks < 4; ++ks)
                        acc = __builtin_amdgcn_mfma_f32_16x16x32_bf16(wB[nt][ks], xf[ks], acc, 0, 0, 0);
                    const int tok = mt * 16 + l16;
                    if (tok < 49) {
                        float4 v; v.x = acc[0] + qb4[nt].x; v.y = acc[1] + qb4[nt].y;
                        v.z = acc[2] + qb4[nt].z; v.w = acc[3] + qb4[nt].w;
                        *(ushort4*)&pool[QK_OFF + tok * QKP + chB + lg * 4] = cvt4(v);
                    }
                } else {
#pragma unroll
                    for (int ks = 0; ks < 4; ++ks)
                        acc = __builtin_amdgcn_mfma_f32_16x16x32_bf16(xf[ks], wB[nt][ks], acc, 0, 0, 0);
                    const float vb = qb4[nt].x;
                    float4 v; v.x = acc[0] + vb; v.y = acc[1] + vb;
                    v.z = acc[2] + vb; v.w = acc[3] + vb;
                    *(ushort4*)&pool[VT_OFF + (chB - 256 + l16) * VTP + mt * 16 + lg * 4] = cvt4(v);
                }
            }
        }
        __syncthreads();   // BAR1: q/k/v visible; xa free (consumed)

        // -------- attention: S' = K * Q^T (softmax over in-lane kt) --------
        bf16x8 ak[4];
#pragma unroll
        for (int mt = 0; mt < 4; ++mt)
            ak[mt] = *(const bf16x8*)&pool[QK_OFF + (mt * 16 + l16) * QKP + 128 + h * 32 + lg * 8];

        float inv[2];
        unsigned pk[2][4][2];
#pragma unroll
        for (int nt = 0; nt < 2; ++nt) {
            const bf16x8 bq = *(const bf16x8*)&pool[QK_OFF + (mh * 32 + nt * 16 + l16) * QKP + h * 32 + lg * 8];
            f32x4 S[4];
#pragma unroll
            for (int mt = 0; mt < 4; ++mt)
                S[mt] = __builtin_amdgcn_mfma_f32_16x16x32_bf16(ak[mt], bq, (f32x4){0.f,0.f,0.f,0.f}, 0, 0, 0);

            const int qt = mh * 32 + nt * 16 + l16;
            const bool qok = (qt < 49);
            const int qrow = qok ? qt : 48;
            float lv[4][4];
#pragma unroll
            for (int mt = 0; mt < 4; ++mt) {
                const float4 mm = *(const float4*)&maskF[qrow * MSP + mt * 16 + lg * 4];
                const unsigned b0 = biasP[nt][mt][0], b1 = biasP[nt][mt][1];
                const float bb0 = __uint_as_float(b0 << 16);
                const float bb1 = __uint_as_float(b0 & 0xffff0000u);
                const float bb2 = __uint_as_float(b1 << 16);
                const float bb3 = __uint_as_float(b1 & 0xffff0000u);
                const int kt0 = mt * 16 + lg * 4;
                lv[mt][0] = (qok && kt0 + 0 < 49) ? (S[mt][0] + bb0 + mm.x) : -1e30f;
                lv[mt][1] = (qok && kt0 + 1 < 49) ? (S[mt][1] + bb1 + mm.y) : -1e30f;
                lv[mt][2] = (qok && kt0 + 2 < 49) ? (S[mt][2] + bb2 + mm.z) : -1e30f;
                lv[mt][3] = (qok && kt0 + 3 < 49) ? (S[mt][3] + bb3 + mm.w) : -1e30f;
            }
            float mx = lv[0][0];
#pragma unroll
            for (int mt = 0; mt < 4; ++mt)
#pragma unroll
                for (int r = 0; r < 4; ++r) mx = fmaxf(mx, lv[mt][r]);
            mx = fmaxf(mx, __shfl_xor(mx, 16));
            mx = fmaxf(mx, __shfl_xor(mx, 32));
            float sum = 0.f;
#pragma unroll
            for (int mt = 0; mt < 4; ++mt)
#pragma unroll
                for (int r = 0; r < 4; ++r) {
                    const float p = exp2f(lv[mt][r] - mx);
                    lv[mt][r] = p;
                    sum += p;
                }
            sum += __shfl_xor(sum, 16);
            sum += __shfl_xor(sum, 32);
            inv[nt] = 1.0f / sum;
#pragma unroll
            for (int mt = 0; mt < 4; ++mt) {
                pk[nt][mt][0] = pack2bf(lv[mt][0], lv[mt][1]);
                pk[nt][mt][1] = pack2bf(lv[mt][2], lv[mt][3]);
            }
        }

        // -------- PV: O' = V^T * P^T (per-wave LDS P round-trips) --------
        f32x4 O[2][2];   // [dim-tile][tok-tile]
#pragma unroll
        for (int i = 0; i < 2; ++i)
#pragma unroll
            for (int j = 0; j < 2; ++j) O[i][j] = (f32x4){0.f, 0.f, 0.f, 0.f};
        const int psb = PS_OFF + wave * 16 * PSP;
#pragma unroll
        for (int kh = 0; kh < 2; ++kh) {
            bf16x8 bv[2];
#pragma unroll
            for (int i = 0; i < 2; ++i)
                bv[i] = *(const bf16x8*)&pool[VT_OFF + (h * 32 + i * 16 + l16) * VTP + kh * 32 + lg * 8];
#pragma unroll
            for (int j = 0; j < 2; ++j) {
                uint2 t0, t1;
                t0.x = pk[j][2 * kh + 0][0]; t0.y = pk[j][2 * kh + 0][1];
                t1.x = pk[j][2 * kh + 1][0]; t1.y = pk[j][2 * kh + 1][1];
                *(uint2*)&pool[psb + l16 * PSP + lg * 4]      = t0;
                *(uint2*)&pool[psb + l16 * PSP + 16 + lg * 4] = t1;
                asm volatile("s_waitcnt lgkmcnt(0)" ::: "memory");
                __builtin_amdgcn_sched_barrier(0);
                const bf16x8 pa = *(const bf16x8*)&pool[psb + l16 * PSP + lg * 8];
#pragma unroll
                for (int i = 0; i < 2; ++i)
                    O[i][j] = __builtin_amdgcn_mfma_f32_16x16x32_bf16(bv[i], pa, O[i][j], 0, 0, 0);
            }
        }
        // attn-out -> xa (row write along dims), fold 1/sum
#pragma unroll
        for (int j = 0; j < 2; ++j) {
            const int tok = mh * 32 + j * 16 + l16;
            if (tok < 49) {
#pragma unroll
                for (int i = 0; i < 2; ++i) {
                    float4 v;
                    v.x = O[i][j][0] * inv[j]; v.y = O[i][j][1] * inv[j];
                    v.z = O[i][j][2] * inv[j]; v.w = O[i][j][3] * inv[j];
                    *(ushort4*)&pool[XA_OFF + tok * XAP + h * 32 + i * 16 + lg * 4] = cvt4(v);
                }
            }
        }
        __syncthreads();   // BAR2: attn-out visible; maskF free

        // stage next window's mask (global -> LDS; consumed after next BAR1)
        if (pf) {
            const float* mp1 = mask + (size_t)((win + 1) & 1023) * 2401;
            for (int e = tid; e < 2401; e += THREADS)
                maskF[(e / 49) * MSP + (e % 49)] = mp1[e] * LOG2E;
        }

        // -------- proj: out^T = proj_w * aout^T (coalesced float4 store) --------
        bf16x8 wp_[4];
        {
            uintptr_t wpu = (uintptr_t)wpr;
            asm volatile("" : "+s"(wpu));
            const unsigned short* wpx = (const unsigned short*)wpu;
#pragma unroll
            for (int ks = 0; ks < 4; ++ks)
                wp_[ks] = *(const bf16x8*)&wpx[(size_t)((wave * 4 + ks) * 64 + lane) * 8];
        }
#pragma unroll
        for (int nt4 = 0; nt4 < 4; ++nt4) {
            f32x4 pc = (f32x4){0.f, 0.f, 0.f, 0.f};
#pragma unroll
            for (int ks = 0; ks < 4; ++ks) {
                const bf16x8 bfr = *(const bf16x8*)&pool[XA_OFF + (nt4 * 16 + l16) * XAP + ks * 32 + lg * 8];
                pc = __builtin_amdgcn_mfma_f32_16x16x32_bf16(wp_[ks], bfr, pc, 0, 0, 0);
            }
            const int tok = nt4 * 16 + l16;
            if (tok < 49) {
                float4 o;
                o.x = pc[0] + pb.x; o.y = pc[1] + pb.y;
                o.z = pc[2] + pb.z; o.w = pc[3] + pb.w;
                *(float4*)(out + ((size_t)win * 49 + tok) * 128 + wave * 16 + lg * 4) = o;
            }
        }
        __syncthreads();   // BAR3: proj's xa reads done

        // stage next window's x (global -> cvt -> LDS)
        if (pf) {
            const float* xp1 = x + (size_t)(win + 1) * 6272;
#pragma unroll
            for (int it = 0; it < 4; ++it) {
                const int e = it * 2048 + tid * 4;
                if (e < 6272) {
                    float4 v = *(const float4*)(xp1 + e);
                    *(ushort4*)&pool[XA_OFF + (e >> 7) * XAP + (e & 127)] = cvt4(v);
                }
            }
        }
        __syncthreads();   // BAR4: next window's x staged
    }
}

extern "C" void kernel_launch(void* const* d_in, const int* in_sizes, int n_in,
                              void* d_out, int out_size, void* d_ws, size_t ws_size,
                              hipStream_t stream) {
    const float* x          = (const float*)d_in[0];
    const float* mask       = (const float*)d_in[1];
    const float* qkv_w      = (const float*)d_in[2];
    const float* qkv_b      = (const float*)d_in[3];
    const float* proj_w     = (const float*)d_in[4];
    const float* proj_b     = (const float*)d_in[5];
    const float* bias_table = (const float*)d_in[6];
    const int*   rel_index  = (const int*)d_in[7];
    float* out = (float*)d_out;
    (void)in_sizes; (void)n_in; (void)ws_size; (void)out_size;

    unsigned short* wq = (unsigned short*)d_ws;
    unsigned short* wp = wq + WQ_USHORTS;

    prep_weights<<<dim3(16), dim3(512), 0, stream>>>(qkv_w, proj_w, wq, wp);
    winattn_kernel<<<dim3(NBLK), dim3(THREADS), 0, stream>>>(
        x, mask, wq, wp, qkv_b, proj_b, bias_table, rel_index, out);
}

// Round 4
// 616.871 us; speedup vs baseline: 2.0015x; 1.2045x over previous
//
#include <hip/hip_runtime.h>
#include <hip/hip_bf16.h>

#define THREADS 512
#define WPB 8
#define NWIN 16384
#define NBLK (NWIN / WPB)

typedef short bf16x8 __attribute__((ext_vector_type(8)));
typedef float f32x4 __attribute__((ext_vector_type(4)));

// ---- LDS pool (ushort units). Deliberate over-reads of padded MFMA rows land
// in the next region (finite bf16 values, results discarded) — all in-pool. ----
#define XAP 136   // xa: [49][136] bf16  (x staging, then attn-out)
#define QKP 264   // qk: [49][264] bf16  (cols 0..255 = q|k channels)
#define VTP 72    // vt: [128][72] bf16  (rows = dims, cols = tokens)
#define PSP 40    // ps: per-wave [16][40] bf16 P staging
#define MSP 68    // maskF: [49][68] f32 (pre-scaled by log2e)

#define XA_OFF 0
#define QK_OFF 6664
#define VT_OFF 19600
#define PS_OFF 28816
#define MS_OFF 33936            // ushort offset; cast to float* (byte 67872, 16B aligned)
#define POOL_USHORTS 40600      // 81,200 bytes -> 81,408 alloc -> 2 blocks/CU

#define LOG2E 1.4426950408889634f
#define SCALE_Q 0.17677669529663689f   // 32^-0.5

// ws layout: wq = 96 fragment-groups (wave*3+nt)*4+ks, 64 lanes, 8 bf16 each
//            wp = 32 fragment-groups (wave*4+ks),      64 lanes, 8 bf16 each
#define WQ_USHORTS (96 * 64 * 8)
#define WP_USHORTS (32 * 64 * 8)

static __device__ __forceinline__ unsigned short f2bf(float x) {
    union { __hip_bfloat16 b; unsigned short u; } c;
    c.b = __float2bfloat16(x);
    return c.u;
}
static __device__ __forceinline__ unsigned pack2bf(float lo, float hi) {
    return (unsigned)f2bf(lo) | ((unsigned)f2bf(hi) << 16);
}
static __device__ __forceinline__ ushort4 cvt4(float4 v) {
    ushort4 u; u.x = f2bf(v.x); u.y = f2bf(v.y); u.z = f2bf(v.z); u.w = f2bf(v.w);
    return u;
}

// ---------------- prep: fp32 weights -> pre-swizzled bf16 fragments in ws ----------------
__global__ __launch_bounds__(512)
void prep_weights(const float* __restrict__ qkv_w, const float* __restrict__ proj_w,
                  unsigned short* __restrict__ wq, unsigned short* __restrict__ wp)
{
    const int t = blockIdx.x * 512 + threadIdx.x;
    if (t < 96 * 64) {
        const int lane = t & 63, g = t >> 6;
        const int l16 = lane & 15, lg = lane >> 4;
        const int ks = g & 3, wn = g >> 2;                 // wn = wave*3+nt
        const int ch = wn * 16 + l16;                      // qkv output channel
        const float s = (ch < 128) ? (SCALE_Q * LOG2E) : 1.0f;
        const float* p = qkv_w + (size_t)ch * 128 + ks * 32 + lg * 8;
        bf16x8 f;
#pragma unroll
        for (int j = 0; j < 8; ++j) f[j] = (short)f2bf(p[j] * s);
        *(bf16x8*)&wq[(size_t)t * 8] = f;
    } else if (t < 96 * 64 + 32 * 64) {
        const int t2 = t - 96 * 64;
        const int lane = t2 & 63, g = t2 >> 6;             // g = wave*4+ks
        const int l16 = lane & 15, lg = lane >> 4;
        const int ks = g & 3, wv = g >> 2;
        const float* p = proj_w + (size_t)(wv * 16 + l16) * 128 + ks * 32 + lg * 8;
        bf16x8 f;
#pragma unroll
        for (int j = 0; j < 8; ++j) f[j] = (short)f2bf(p[j]);
        *(bf16x8*)&wp[(size_t)t2 * 8] = f;
    }
}

__global__ __launch_bounds__(THREADS, 2)
void winattn_kernel(const float* __restrict__ x, const float* __restrict__ mask,
                    const unsigned short* __restrict__ wq, const unsigned short* __restrict__ wpr,
                    const float* __restrict__ qkv_b, const float* __restrict__ proj_b,
                    const float* __restrict__ bias_table, const int* __restrict__ rel_index,
                    float* __restrict__ out)
{
    __shared__ __align__(16) unsigned short pool[POOL_USHORTS];
    float* maskF = (float*)&pool[MS_OFF];

    const int tid  = threadIdx.x;
    const int wave = tid >> 6;
    const int lane = tid & 63;
    const int lg   = lane >> 4;
    const int l16  = lane & 15;
    const int h    = wave >> 1;      // head
    const int mh   = wave & 1;       // q-half (32 tokens)

    // ---------------- persistent per-block state (20 VGPRs) ----------------
    // relative-position bias, packed bf16 pairs, pre-scaled by LOG2E.
    unsigned biasP[2][4][2];
#pragma unroll
    for (int nt = 0; nt < 2; ++nt) {
        int qt = mh * 32 + nt * 16 + l16; if (qt > 48) qt = 48;
#pragma unroll
        for (int mt = 0; mt < 4; ++mt) {
#pragma unroll
            for (int w2 = 0; w2 < 2; ++w2) {
                float b[2];
#pragma unroll
                for (int r = 0; r < 2; ++r) {
                    int kt = mt * 16 + lg * 4 + w2 * 2 + r; if (kt > 48) kt = 48;
                    const int idx = rel_index[qt * 49 + kt];
                    b[r] = bias_table[idx * 4 + h] * LOG2E;
                }
                biasP[nt][mt][w2] = pack2bf(b[0], b[1]);
            }
        }
    }
    const float4 pb = *(const float4*)(proj_b + wave * 16 + lg * 4);

    const int win0 = blockIdx.x * WPB;

    // ---------------- prologue: zero qk+vt, stage window 0 ----------------
    {
        unsigned* p32 = (unsigned*)pool;
        for (int i = QK_OFF / 2 + tid; i < QK_OFF / 2 + (12936 + 9216) / 2; i += THREADS)
            p32[i] = 0;
    }
#pragma unroll
    for (int it = 0; it < 4; ++it) {
        const int e = it * 2048 + tid * 4;
        if (e < 6272) {
            float4 v = *(const float4*)(x + (size_t)win0 * 6272 + e);
            *(ushort4*)&pool[XA_OFF + (e >> 7) * XAP + (e & 127)] = cvt4(v);
        }
    }
    {
        const float* mp0 = mask + (size_t)(win0 & 1023) * 2401;
        for (int e = tid; e < 2401; e += THREADS)
            maskF[(e / 49) * MSP + (e % 49)] = mp0[e] * LOG2E;
    }
    __syncthreads();

    for (int w = 0; w < WPB; ++w) {
        const int win = win0 + w;
        const bool pf = (w + 1 < WPB);

        // -------- QKV GEMM (mt-major; per-tile operand orientation) --------
        // Weight fragments reloaded from L2 each window (pointer laundered so
        // LICM can't hoist them into 48 persistent VGPRs).
        bf16x8 wB[3][4];
        {
            uintptr_t wqu = (uintptr_t)wq;
            asm volatile("" : "+s"(wqu));
            const unsigned short* wqx = (const unsigned short*)wqu;
#pragma unroll
            for (int nt = 0; nt < 3; ++nt)
#pragma unroll
                for (int ks = 0; ks < 4; ++ks)
                    wB[nt][ks] = *(const bf16x8*)&wqx[(size_t)(((wave * 3 + nt) * 4 + ks) * 64 + lane) * 8];
        }
        float4 qb4[3];
#pragma unroll
        for (int nt = 0; nt < 3; ++nt) {
            const int chB = wave * 48 + nt * 16;
            if (chB < 256) {
                float4 b = *(const float4*)(qkv_b + chB + lg * 4);
                if (chB < 128) { b.x *= SCALE_Q * LOG2E; b.y *= SCALE_Q * LOG2E;
                                 b.z *= SCALE_Q * LOG2E; b.w *= SCALE_Q * LOG2E; }
                qb4[nt] = b;
            } else {
                qb4[nt].x = qkv_b[chB + l16];
            }
        }
#pragma unroll
        for (int mt = 0; mt < 4; ++mt) {
            bf16x8 xf[4];
#pragma unroll
            for (int ks = 0; ks < 4; ++ks)
                xf[ks] = *(const bf16x8*)&pool[XA_OFF + (mt * 16 + l16) * XAP + ks * 32 + lg * 8];
#pragma unroll
            for (int nt = 0; nt < 3; ++nt) {
                const int chB = wave * 48 + nt * 16;
                f32x4 acc = (f32x4){0.f, 0.f, 0.f, 0.f};
                if (chB < 256) {
#pragma unroll
                    for (int ks = 0; ks < 4; ++ks)
                        acc = __builtin_amdgcn_mfma_f32_16x16x32_bf16(wB[nt][ks], xf[ks], acc, 0, 0, 0);
                    const int tok = mt * 16 + l16;
                    if (tok < 49) {
                        float4 v; v.x = acc[0] + qb4[nt].x; v.y = acc[1] + qb4[nt].y;
                        v.z = acc[2] + qb4[nt].z; v.w = acc[3] + qb4[nt].w;
                        *(ushort4*)&pool[QK_OFF + tok * QKP + chB + lg * 4] = cvt4(v);
                    }
                } else {
#pragma unroll
                    for (int ks = 0; ks < 4; ++ks)
                        acc = __builtin_amdgcn_mfma_f32_16x16x32_bf16(xf[ks], wB[nt][ks], acc, 0, 0, 0);
                    const float vb = qb4[nt].x;
                    float4 v; v.x = acc[0] + vb; v.y = acc[1] + vb;
                    v.z = acc[2] + vb; v.w = acc[3] + vb;
                    *(ushort4*)&pool[VT_OFF + (chB - 256 + l16) * VTP + mt * 16 + lg * 4] = cvt4(v);
                }
            }
        }
        __syncthreads();   // BAR1: q/k/v visible; xa free (consumed)

        // -------- attention: S' = K * Q^T (softmax over in-lane kt) --------
        bf16x8 ak[4];
#pragma unroll
        for (int mt = 0; mt < 4; ++mt)
            ak[mt] = *(const bf16x8*)&pool[QK_OFF + (mt * 16 + l16) * QKP + 128 + h * 32 + lg * 8];

        float inv[2];
        unsigned pk[2][4][2];
#pragma unroll
        for (int nt = 0; nt < 2; ++nt) {
            const bf16x8 bq = *(const bf16x8*)&pool[QK_OFF + (mh * 32 + nt * 16 + l16) * QKP + h * 32 + lg * 8];
            f32x4 S[4];
#pragma unroll
            for (int mt = 0; mt < 4; ++mt)
                S[mt] = __builtin_amdgcn_mfma_f32_16x16x32_bf16(ak[mt], bq, (f32x4){0.f,0.f,0.f,0.f}, 0, 0, 0);

            const int qt = mh * 32 + nt * 16 + l16;
            const bool qok = (qt < 49);
            const int qrow = qok ? qt : 48;
            float lv[4][4];
#pragma unroll
            for (int mt = 0; mt < 4; ++mt) {
                const float4 mm = *(const float4*)&maskF[qrow * MSP + mt * 16 + lg * 4];
                const unsigned b0 = biasP[nt][mt][0], b1 = biasP[nt][mt][1];
                const float bb0 = __uint_as_float(b0 << 16);
                const float bb1 = __uint_as_float(b0 & 0xffff0000u);
                const float bb2 = __uint_as_float(b1 << 16);
                const float bb3 = __uint_as_float(b1 & 0xffff0000u);
                const int kt0 = mt * 16 + lg * 4;
                lv[mt][0] = (qok && kt0 + 0 < 49) ? (S[mt][0] + bb0 + mm.x) : -1e30f;
                lv[mt][1] = (qok && kt0 + 1 < 49) ? (S[mt][1] + bb1 + mm.y) : -1e30f;
                lv[mt][2] = (qok && kt0 + 2 < 49) ? (S[mt][2] + bb2 + mm.z) : -1e30f;
                lv[mt][3] = (qok && kt0 + 3 < 49) ? (S[mt][3] + bb3 + mm.w) : -1e30f;
            }
            float mx = lv[0][0];
#pragma unroll
            for (int mt = 0; mt < 4; ++mt)
#pragma unroll
                for (int r = 0; r < 4; ++r) mx = fmaxf(mx, lv[mt][r]);
            mx = fmaxf(mx, __shfl_xor(mx, 16));
            mx = fmaxf(mx, __shfl_xor(mx, 32));
            float sum = 0.f;
#pragma unroll
            for (int mt = 0; mt < 4; ++mt)
#pragma unroll
                for (int r = 0; r < 4; ++r) {
                    const float p = exp2f(lv[mt][r] - mx);
                    lv[mt][r] = p;
                    sum += p;
                }
            sum += __shfl_xor(sum, 16);
            sum += __shfl_xor(sum, 32);
            inv[nt] = 1.0f / sum;
#pragma unroll
            for (int mt = 0; mt < 4; ++mt) {
                pk[nt][mt][0] = pack2bf(lv[mt][0], lv[mt][1]);
                pk[nt][mt][1] = pack2bf(lv[mt][2], lv[mt][3]);
            }
        }

        // -------- PV: O' = V^T * P^T (per-wave LDS P round-trips) --------
        f32x4 O[2][2];   // [dim-tile][tok-tile]
#pragma unroll
        for (int i = 0; i < 2; ++i)
#pragma unroll
            for (int j = 0; j < 2; ++j) O[i][j] = (f32x4){0.f, 0.f, 0.f, 0.f};
        const int psb = PS_OFF + wave * 16 * PSP;
#pragma unroll
        for (int kh = 0; kh < 2; ++kh) {
            bf16x8 bv[2];
#pragma unroll
            for (int i = 0; i < 2; ++i)
                bv[i] = *(const bf16x8*)&pool[VT_OFF + (h * 32 + i * 16 + l16) * VTP + kh * 32 + lg * 8];
#pragma unroll
            for (int j = 0; j < 2; ++j) {
                uint2 t0, t1;
                t0.x = pk[j][2 * kh + 0][0]; t0.y = pk[j][2 * kh + 0][1];
                t1.x = pk[j][2 * kh + 1][0]; t1.y = pk[j][2 * kh + 1][1];
                *(uint2*)&pool[psb + l16 * PSP + lg * 4]      = t0;
                *(uint2*)&pool[psb + l16 * PSP + 16 + lg * 4] = t1;
                asm volatile("s_waitcnt lgkmcnt(0)" ::: "memory");
                __builtin_amdgcn_sched_barrier(0);
                const bf16x8 pa = *(const bf16x8*)&pool[psb + l16 * PSP + lg * 8];
#pragma unroll
                for (int i = 0; i < 2; ++i)
                    O[i][j] = __builtin_amdgcn_mfma_f32_16x16x32_bf16(bv[i], pa, O[i][j], 0, 0, 0);
            }
        }
        // attn-out -> xa (row write along dims), fold 1/sum
#pragma unroll
        for (int j = 0; j < 2; ++j) {
            const int tok = mh * 32 + j * 16 + l16;
            if (tok < 49) {
#pragma unroll
                for (int i = 0; i < 2; ++i) {
                    float4 v;
                    v.x = O[i][j][0] * inv[j]; v.y = O[i][j][1] * inv[j];
                    v.z = O[i][j][2] * inv[j]; v.w = O[i][j][3] * inv[j];
                    *(ushort4*)&pool[XA_OFF + tok * XAP + h * 32 + i * 16 + lg * 4] = cvt4(v);
                }
            }
        }
        __syncthreads();   // BAR2: attn-out visible; maskF free

        // stage next window's mask (global -> LDS; consumed after next BAR1)
        if (pf) {
            const float* mp1 = mask + (size_t)((win + 1) & 1023) * 2401;
            for (int e = tid; e < 2401; e += THREADS)
                maskF[(e / 49) * MSP + (e % 49)] = mp1[e] * LOG2E;
        }

        // -------- proj: out^T = proj_w * aout^T (coalesced float4 store) --------
        bf16x8 wp_[4];
        {
            uintptr_t wpu = (uintptr_t)wpr;
            asm volatile("" : "+s"(wpu));
            const unsigned short* wpx = (const unsigned short*)wpu;
#pragma unroll
            for (int ks = 0; ks < 4; ++ks)
                wp_[ks] = *(const bf16x8*)&wpx[(size_t)((wave * 4 + ks) * 64 + lane) * 8];
        }
#pragma unroll
        for (int nt4 = 0; nt4 < 4; ++nt4) {
            f32x4 pc = (f32x4){0.f, 0.f, 0.f, 0.f};
#pragma unroll
            for (int ks = 0; ks < 4; ++ks) {
                const bf16x8 bfr = *(const bf16x8*)&pool[XA_OFF + (nt4 * 16 + l16) * XAP + ks * 32 + lg * 8];
                pc = __builtin_amdgcn_mfma_f32_16x16x32_bf16(wp_[ks], bfr, pc, 0, 0, 0);
            }
            const int tok = nt4 * 16 + l16;
            if (tok < 49) {
                float4 o;
                o.x = pc[0] + pb.x; o.y = pc[1] + pb.y;
                o.z = pc[2] + pb.z; o.w = pc[3] + pb.w;
                *(float4*)(out + ((size_t)win * 49 + tok) * 128 + wave * 16 + lg * 4) = o;
            }
        }
        __syncthreads();   // BAR3: proj's xa reads done

        // stage next window's x (global -> cvt -> LDS)
        if (pf) {
            const float* xp1 = x + (size_t)(win + 1) * 6272;
#pragma unroll
            for (int it = 0; it < 4; ++it) {
                const int e = it * 2048 + tid * 4;
                if (e < 6272) {
                    float4 v = *(const float4*)(xp1 + e);
                    *(ushort4*)&pool[XA_OFF + (e >> 7) * XAP + (e & 127)] = cvt4(v);
                }
            }
        }
        __syncthreads();   // BAR4: next window's x staged
    }
}

extern "C" void kernel_launch(void* const* d_in, const int* in_sizes, int n_in,
                              void* d_out, int out_size, void* d_ws, size_t ws_size,
                              hipStream_t stream) {
    const float* x          = (const float*)d_in[0];
    const float* mask       = (const float*)d_in[1];
    const float* qkv_w      = (const float*)d_in[2];
    const float* qkv_b      = (const float*)d_in[3];
    const float* proj_w     = (const float*)d_in[4];
    const float* proj_b     = (const float*)d_in[5];
    const float* bias_table = (const float*)d_in[6];
    const int*   rel_index  = (const int*)d_in[7];
    float* out = (float*)d_out;
    (void)in_sizes; (void)n_in; (void)ws_size; (void)out_size;

    unsigned short* wq = (unsigned short*)d_ws;
    unsigned short* wp = wq + WQ_USHORTS;

    prep_weights<<<dim3(16), dim3(512), 0, stream>>>(qkv_w, proj_w, wq, wp);
    winattn_kernel<<<dim3(NBLK), dim3(THREADS), 0, stream>>>(
        x, mask, wq, wp, qkv_b, proj_b, bias_table, rel_index, out);
}

// Round 5
// 530.673 us; speedup vs baseline: 2.3266x; 1.1624x over previous
//
#include <hip/hip_runtime.h>
#include <hip/hip_bf16.h>

#define THREADS 512
#define WPB 8
#define NWIN 16384
#define NBLK (NWIN / WPB)

typedef short bf16x8 __attribute__((ext_vector_type(8)));
typedef float f32x4 __attribute__((ext_vector_type(4)));

// ---- LDS pool (ushort units). Deliberate over-reads of padded MFMA rows land
// in the next region (finite bf16 values, results discarded) — all in-pool. ----
#define XAP 136   // xa: [49][136] bf16  (x staging, then attn-out)
#define QKP 264   // qk: [49][264] bf16  (cols 0..255 = q|k channels)
#define VTP 72    // vt: [128][72] bf16  (rows = dims, cols = tokens)
#define PSP 40    // ps: per-wave [16][40] bf16 P staging
#define MSP 68    // maskF: [49][68] f32 (pre-scaled by log2e)

#define XA_OFF 0
#define QK_OFF 6664
#define VT_OFF 19600
#define PS_OFF 28816
#define MS_OFF 33936            // ushort offset; cast to float* (byte 67872, 16B aligned)
#define POOL_USHORTS 40600      // 81,200 bytes -> 81,408 alloc

#define LOG2E 1.4426950408889634f
#define SCALE_Q 0.17677669529663689f   // 32^-0.5

// ws layout: wq = 96 fragment-groups (wave*3+nt)*4+ks, 64 lanes, 8 bf16 each
//            wp = 32 fragment-groups (wave*4+ks),      64 lanes, 8 bf16 each
#define WQ_USHORTS (96 * 64 * 8)
#define WP_USHORTS (32 * 64 * 8)

static __device__ __forceinline__ unsigned short f2bf(float x) {
    union { __hip_bfloat16 b; unsigned short u; } c;
    c.b = __float2bfloat16(x);
    return c.u;
}
static __device__ __forceinline__ unsigned pack2bf(float lo, float hi) {
    return (unsigned)f2bf(lo) | ((unsigned)f2bf(hi) << 16);
}
static __device__ __forceinline__ ushort4 cvt4(float4 v) {
    ushort4 u; u.x = f2bf(v.x); u.y = f2bf(v.y); u.z = f2bf(v.z); u.w = f2bf(v.w);
    return u;
}

// ---------------- prep: fp32 weights -> pre-swizzled bf16 fragments in ws ----------------
__global__ __launch_bounds__(512)
void prep_weights(const float* __restrict__ qkv_w, const float* __restrict__ proj_w,
                  unsigned short* __restrict__ wq, unsigned short* __restrict__ wp)
{
    const int t = blockIdx.x * 512 + threadIdx.x;
    if (t < 96 * 64) {
        const int lane = t & 63, g = t >> 6;
        const int l16 = lane & 15, lg = lane >> 4;
        const int ks = g & 3, wn = g >> 2;                 // wn = wave*3+nt
        const int ch = wn * 16 + l16;                      // qkv output channel
        const float s = (ch < 128) ? (SCALE_Q * LOG2E) : 1.0f;
        const float* p = qkv_w + (size_t)ch * 128 + ks * 32 + lg * 8;
        bf16x8 f;
#pragma unroll
        for (int j = 0; j < 8; ++j) f[j] = (short)f2bf(p[j] * s);
        *(bf16x8*)&wq[(size_t)t * 8] = f;
    } else if (t < 96 * 64 + 32 * 64) {
        const int t2 = t - 96 * 64;
        const int lane = t2 & 63, g = t2 >> 6;             // g = wave*4+ks
        const int l16 = lane & 15, lg = lane >> 4;
        const int ks = g & 3, wv = g >> 2;
        const float* p = proj_w + (size_t)(wv * 16 + l16) * 128 + ks * 32 + lg * 8;
        bf16x8 f;
#pragma unroll
        for (int j = 0; j < 8; ++j) f[j] = (short)f2bf(p[j]);
        *(bf16x8*)&wp[(size_t)t2 * 8] = f;
    }
}

__global__ __launch_bounds__(THREADS, 2)
void winattn_kernel(const float* __restrict__ x, const float* __restrict__ mask,
                    const unsigned short* __restrict__ wq, const unsigned short* __restrict__ wpr,
                    const float* __restrict__ qkv_b, const float* __restrict__ proj_b,
                    const float* __restrict__ bias_table, const int* __restrict__ rel_index,
                    float* __restrict__ out)
{
    __shared__ __align__(16) unsigned short pool[POOL_USHORTS];
    float* maskF = (float*)&pool[MS_OFF];

    const int tid  = threadIdx.x;
    const int wave = tid >> 6;
    const int lane = tid & 63;
    const int lg   = lane >> 4;
    const int l16  = lane & 15;
    const int h    = wave >> 1;      // head
    const int mh   = wave & 1;       // q-half (32 tokens)

    // ---------------- persistent per-block state (~32 VGPRs) ----------------
    unsigned biasP[2][4][2];
#pragma unroll
    for (int nt = 0; nt < 2; ++nt) {
        int qt = mh * 32 + nt * 16 + l16; if (qt > 48) qt = 48;
#pragma unroll
        for (int mt = 0; mt < 4; ++mt) {
#pragma unroll
            for (int w2 = 0; w2 < 2; ++w2) {
                float b[2];
#pragma unroll
                for (int r = 0; r < 2; ++r) {
                    int kt = mt * 16 + lg * 4 + w2 * 2 + r; if (kt > 48) kt = 48;
                    const int idx = rel_index[qt * 49 + kt];
                    b[r] = bias_table[idx * 4 + h] * LOG2E;
                }
                biasP[nt][mt][w2] = pack2bf(b[0], b[1]);
            }
        }
    }
    const float4 pb = *(const float4*)(proj_b + wave * 16 + lg * 4);

    const int win0 = blockIdx.x * WPB;

    // ---------------- prologue: zero qk+vt, stage window 0 ----------------
    {
        unsigned* p32 = (unsigned*)pool;
        for (int i = QK_OFF / 2 + tid; i < QK_OFF / 2 + (12936 + 9216) / 2; i += THREADS)
            p32[i] = 0;
    }
#pragma unroll
    for (int it = 0; it < 4; ++it) {
        const int e = it * 2048 + tid * 4;
        if (e < 6272) {
            float4 v = *(const float4*)(x + (size_t)win0 * 6272 + e);
            *(ushort4*)&pool[XA_OFF + (e >> 7) * XAP + (e & 127)] = cvt4(v);
        }
    }
    {
        const float* mp0 = mask + (size_t)(win0 & 1023) * 2401;
        for (int e = tid; e < 2401; e += THREADS)
            maskF[(e / 49) * MSP + (e % 49)] = mp0[e] * LOG2E;
    }
    __syncthreads();

    for (int w = 0; w < WPB; ++w) {
        const int win = win0 + w;
        const bool pf = (w + 1 < WPB);

        // -------- issue next-window prefetch (x, mask) into registers --------
        float4 xr[4];
        float  mr[5];
        if (pf) {
            const float* xp1 = x + (size_t)(win + 1) * 6272;
#pragma unroll
            for (int it = 0; it < 4; ++it) {
                const int e = it * 2048 + tid * 4;
                if (e < 6272) xr[it] = *(const float4*)(xp1 + e);
            }
            const float* mp1 = mask + (size_t)((win + 1) & 1023) * 2401;
#pragma unroll
            for (int it = 0; it < 5; ++it) {
                const int e = it * THREADS + tid;
                if (e < 2401) mr[it] = mp1[e];
            }
        }

        // -------- QKV GEMM, nt-outer (one 16-reg wB tile live at a time) --------
        {
            uintptr_t wqu = (uintptr_t)wq;
            asm volatile("" : "+s"(wqu));
            const unsigned short* wqx = (const unsigned short*)wqu;
#pragma unroll
            for (int nt = 0; nt < 3; ++nt) {
                bf16x8 wB[4];
#pragma unroll
                for (int ks = 0; ks < 4; ++ks)
                    wB[ks] = *(const bf16x8*)&wqx[(size_t)(((wave * 3 + nt) * 4 + ks) * 64 + lane) * 8];
                const int chB = wave * 48 + nt * 16;
                float4 qb4;
                if (chB < 256) {
                    qb4 = *(const float4*)(qkv_b + chB + lg * 4);
                    if (chB < 128) { qb4.x *= SCALE_Q * LOG2E; qb4.y *= SCALE_Q * LOG2E;
                                     qb4.z *= SCALE_Q * LOG2E; qb4.w *= SCALE_Q * LOG2E; }
                } else {
                    qb4.x = qkv_b[chB + l16];
                }
#pragma unroll
                for (int mt = 0; mt < 4; ++mt) {
                    bf16x8 xf[4];
#pragma unroll
                    for (int ks = 0; ks < 4; ++ks)
                        xf[ks] = *(const bf16x8*)&pool[XA_OFF + (mt * 16 + l16) * XAP + ks * 32 + lg * 8];
                    f32x4 acc = (f32x4){0.f, 0.f, 0.f, 0.f};
                    if (chB < 256) {
#pragma unroll
                        for (int ks = 0; ks < 4; ++ks)
                            acc = __builtin_amdgcn_mfma_f32_16x16x32_bf16(wB[ks], xf[ks], acc, 0, 0, 0);
                        const int tok = mt * 16 + l16;
                        if (tok < 49) {
                            float4 v; v.x = acc[0] + qb4.x; v.y = acc[1] + qb4.y;
                            v.z = acc[2] + qb4.z; v.w = acc[3] + qb4.w;
                            *(ushort4*)&pool[QK_OFF + tok * QKP + chB + lg * 4] = cvt4(v);
                        }
                    } else {
#pragma unroll
                        for (int ks = 0; ks < 4; ++ks)
                            acc = __builtin_amdgcn_mfma_f32_16x16x32_bf16(xf[ks], wB[ks], acc, 0, 0, 0);
                        const float vb = qb4.x;
                        float4 v; v.x = acc[0] + vb; v.y = acc[1] + vb;
                        v.z = acc[2] + vb; v.w = acc[3] + vb;
                        *(ushort4*)&pool[VT_OFF + (chB - 256 + l16) * VTP + mt * 16 + lg * 4] = cvt4(v);
                    }
                }
            }
        }
        __syncthreads();   // BAR1: q/k/v visible; xa free (consumed)

        // convert prefetched x to bf16 (xr dies here; waits happened during QKV)
        ushort4 xb[4];
        if (pf) {
#pragma unroll
            for (int it = 0; it < 4; ++it) xb[it] = cvt4(xr[it]);
        }

        // -------- attention: S' = K * Q^T (softmax over in-lane kt) --------
        bf16x8 ak[4];
#pragma unroll
        for (int mt = 0; mt < 4; ++mt)
            ak[mt] = *(const bf16x8*)&pool[QK_OFF + (mt * 16 + l16) * QKP + 128 + h * 32 + lg * 8];

        float inv[2];
        unsigned pk[2][4][2];
#pragma unroll
        for (int nt = 0; nt < 2; ++nt) {
            const bf16x8 bq = *(const bf16x8*)&pool[QK_OFF + (mh * 32 + nt * 16 + l16) * QKP + h * 32 + lg * 8];
            f32x4 S[4];
#pragma unroll
            for (int mt = 0; mt < 4; ++mt)
                S[mt] = __builtin_amdgcn_mfma_f32_16x16x32_bf16(ak[mt], bq, (f32x4){0.f,0.f,0.f,0.f}, 0, 0, 0);

            const int qt = mh * 32 + nt * 16 + l16;
            const bool qok = (qt < 49);
            const int qrow = qok ? qt : 48;
            float lv[4][4];
#pragma unroll
            for (int mt = 0; mt < 4; ++mt) {
                const float4 mm = *(const float4*)&maskF[qrow * MSP + mt * 16 + lg * 4];
                const unsigned b0 = biasP[nt][mt][0], b1 = biasP[nt][mt][1];
                const float bb0 = __uint_as_float(b0 << 16);
                const float bb1 = __uint_as_float(b0 & 0xffff0000u);
                const float bb2 = __uint_as_float(b1 << 16);
                const float bb3 = __uint_as_float(b1 & 0xffff0000u);
                const int kt0 = mt * 16 + lg * 4;
                lv[mt][0] = (qok && kt0 + 0 < 49) ? (S[mt][0] + bb0 + mm.x) : -1e30f;
                lv[mt][1] = (qok && kt0 + 1 < 49) ? (S[mt][1] + bb1 + mm.y) : -1e30f;
                lv[mt][2] = (qok && kt0 + 2 < 49) ? (S[mt][2] + bb2 + mm.z) : -1e30f;
                lv[mt][3] = (qok && kt0 + 3 < 49) ? (S[mt][3] + bb3 + mm.w) : -1e30f;
            }
            float mx = lv[0][0];
#pragma unroll
            for (int mt = 0; mt < 4; ++mt)
#pragma unroll
                for (int r = 0; r < 4; ++r) mx = fmaxf(mx, lv[mt][r]);
            mx = fmaxf(mx, __shfl_xor(mx, 16));
            mx = fmaxf(mx, __shfl_xor(mx, 32));
            float sum = 0.f;
#pragma unroll
            for (int mt = 0; mt < 4; ++mt)
#pragma unroll
                for (int r = 0; r < 4; ++r) {
                    const float p = exp2f(lv[mt][r] - mx);
                    lv[mt][r] = p;
                    sum += p;
                }
            sum += __shfl_xor(sum, 16);
            sum += __shfl_xor(sum, 32);
            inv[nt] = 1.0f / sum;
#pragma unroll
            for (int mt = 0; mt < 4; ++mt) {
                pk[nt][mt][0] = pack2bf(lv[mt][0], lv[mt][1]);
                pk[nt][mt][1] = pack2bf(lv[mt][2], lv[mt][3]);
            }
        }

        // -------- PV: O' = V^T * P^T (per-wave LDS P round-trips) --------
        f32x4 O[2][2];   // [dim-tile][tok-tile]
#pragma unroll
        for (int i = 0; i < 2; ++i)
#pragma unroll
            for (int j = 0; j < 2; ++j) O[i][j] = (f32x4){0.f, 0.f, 0.f, 0.f};
        const int psb = PS_OFF + wave * 16 * PSP;
#pragma unroll
        for (int kh = 0; kh < 2; ++kh) {
            bf16x8 bv[2];
#pragma unroll
            for (int i = 0; i < 2; ++i)
                bv[i] = *(const bf16x8*)&pool[VT_OFF + (h * 32 + i * 16 + l16) * VTP + kh * 32 + lg * 8];
#pragma unroll
            for (int j = 0; j < 2; ++j) {
                uint2 t0, t1;
                t0.x = pk[j][2 * kh + 0][0]; t0.y = pk[j][2 * kh + 0][1];
                t1.x = pk[j][2 * kh + 1][0]; t1.y = pk[j][2 * kh + 1][1];
                *(uint2*)&pool[psb + l16 * PSP + lg * 4]      = t0;
                *(uint2*)&pool[psb + l16 * PSP + 16 + lg * 4] = t1;
                asm volatile("s_waitcnt lgkmcnt(0)" ::: "memory");
                __builtin_amdgcn_sched_barrier(0);
                const bf16x8 pa = *(const bf16x8*)&pool[psb + l16 * PSP + lg * 8];
#pragma unroll
                for (int i = 0; i < 2; ++i)
                    O[i][j] = __builtin_amdgcn_mfma_f32_16x16x32_bf16(bv[i], pa, O[i][j], 0, 0, 0);
            }
        }
        // attn-out -> xa (row write along dims), fold 1/sum
#pragma unroll
        for (int j = 0; j < 2; ++j) {
            const int tok = mh * 32 + j * 16 + l16;
            if (tok < 49) {
#pragma unroll
                for (int i = 0; i < 2; ++i) {
                    float4 v;
                    v.x = O[i][j][0] * inv[j]; v.y = O[i][j][1] * inv[j];
                    v.z = O[i][j][2] * inv[j]; v.w = O[i][j][3] * inv[j];
                    *(ushort4*)&pool[XA_OFF + tok * XAP + h * 32 + i * 16 + lg * 4] = cvt4(v);
                }
            }
        }
        __syncthreads();   // BAR2: attn-out visible; maskF free

        // store prefetched mask (registers -> LDS; readers finished at BAR2)
        if (pf) {
#pragma unroll
            for (int it = 0; it < 5; ++it) {
                const int e = it * THREADS + tid;
                if (e < 2401) maskF[(e / 49) * MSP + (e % 49)] = mr[it] * LOG2E;
            }
        }

        // -------- proj: out^T = proj_w * aout^T (coalesced float4 store) --------
        bf16x8 wp_[4];
        {
            uintptr_t wpu = (uintptr_t)wpr;
            asm volatile("" : "+s"(wpu));
            const unsigned short* wpx = (const unsigned short*)wpu;
#pragma unroll
            for (int ks = 0; ks < 4; ++ks)
                wp_[ks] = *(const bf16x8*)&wpx[(size_t)((wave * 4 + ks) * 64 + lane) * 8];
        }
#pragma unroll
        for (int nt4 = 0; nt4 < 4; ++nt4) {
            f32x4 pc = (f32x4){0.f, 0.f, 0.f, 0.f};
#pragma unroll
            for (int ks = 0; ks < 4; ++ks) {
                const bf16x8 bfr = *(const bf16x8*)&pool[XA_OFF + (nt4 * 16 + l16) * XAP + ks * 32 + lg * 8];
                pc = __builtin_amdgcn_mfma_f32_16x16x32_bf16(wp_[ks], bfr, pc, 0, 0, 0);
            }
            const int tok = nt4 * 16 + l16;
            if (tok < 49) {
                float4 o;
                o.x = pc[0] + pb.x; o.y = pc[1] + pb.y;
                o.z = pc[2] + pb.z; o.w = pc[3] + pb.w;
                *(float4*)(out + ((size_t)win * 49 + tok) * 128 + wave * 16 + lg * 4) = o;
            }
        }
        __syncthreads();   // BAR3: proj's xa reads done

        // store prefetched x (registers -> LDS)
        if (pf) {
#pragma unroll
            for (int it = 0; it < 4; ++it) {
                const int e = it * 2048 + tid * 4;
                if (e < 6272)
                    *(ushort4*)&pool[XA_OFF + (e >> 7) * XAP + (e & 127)] = xb[it];
            }
        }
        __syncthreads();   // BAR4: next window's x staged
    }
}

extern "C" void kernel_launch(void* const* d_in, const int* in_sizes, int n_in,
                              void* d_out, int out_size, void* d_ws, size_t ws_size,
                              hipStream_t stream) {
    const float* x          = (const float*)d_in[0];
    const float* mask       = (const float*)d_in[1];
    const float* qkv_w      = (const float*)d_in[2];
    const float* qkv_b      = (const float*)d_in[3];
    const float* proj_w     = (const float*)d_in[4];
    const float* proj_b     = (const float*)d_in[5];
    const float* bias_table = (const float*)d_in[6];
    const int*   rel_index  = (const int*)d_in[7];
    float* out = (float*)d_out;
    (void)in_sizes; (void)n_in; (void)ws_size; (void)out_size;

    unsigned short* wq = (unsigned short*)d_ws;
    unsigned short* wp = wq + WQ_USHORTS;

    prep_weights<<<dim3(16), dim3(512), 0, stream>>>(qkv_w, proj_w, wq, wp);
    winattn_kernel<<<dim3(NBLK), dim3(THREADS), 0, stream>>>(
        x, mask, wq, wp, qkv_b, proj_b, bias_table, rel_index, out);
}

// Round 6
// 453.964 us; speedup vs baseline: 2.7197x; 1.1690x over previous
//
#include <hip/hip_runtime.h>
#include <hip/hip_bf16.h>

#define THREADS 512
#define WPB 8
#define NWIN 16384
#define NBLK (NWIN / WPB)

typedef short bf16x8 __attribute__((ext_vector_type(8)));
typedef float f32x4 __attribute__((ext_vector_type(4)));

// ---- LDS pool (ushort units). Deliberate over-reads of padded MFMA rows land
// in the next region (finite bf16 values, results discarded) — all in-pool. ----
#define XAP 136   // xa: [49][136] bf16  (x staging, then attn-out)
#define QKP 264   // qk: [49][264] bf16  (cols 0..255 = q|k channels)
#define VTP 72    // vt: [128][72] bf16  (rows = dims, cols = tokens)
#define PSP 40    // ps: per-wave [16][40] bf16 P staging
#define MSP 68    // maskF: [49][68] f32 (pre-scaled by log2e)

#define XA_OFF 0
#define QK_OFF 6664
#define VT_OFF 19600
#define PS_OFF 28816
#define MS_OFF 33936            // ushort offset; cast to float* (byte 67872, 16B aligned)
#define POOL_USHORTS 40600      // 81,200 bytes -> 81,408 alloc -> 2 blocks/CU

#define LOG2E 1.4426950408889634f
#define SCALE_Q 0.17677669529663689f   // 32^-0.5

// ws layout: wq = 96 fragment-groups (wave*3+nt)*4+ks, 64 lanes, 8 bf16 each
//            wp = 32 fragment-groups (wave*4+ks),      64 lanes, 8 bf16 each
#define WQ_USHORTS (96 * 64 * 8)
#define WP_USHORTS (32 * 64 * 8)

static __device__ __forceinline__ unsigned short f2bf(float x) {
    union { __hip_bfloat16 b; unsigned short u; } c;
    c.b = __float2bfloat16(x);
    return c.u;
}
static __device__ __forceinline__ unsigned pack2bf(float lo, float hi) {
    return (unsigned)f2bf(lo) | ((unsigned)f2bf(hi) << 16);
}
static __device__ __forceinline__ ushort4 cvt4(float4 v) {
    ushort4 u; u.x = f2bf(v.x); u.y = f2bf(v.y); u.z = f2bf(v.z); u.w = f2bf(v.w);
    return u;
}

// ---------------- prep: fp32 weights -> pre-swizzled bf16 fragments in ws ----------------
__global__ __launch_bounds__(512)
void prep_weights(const float* __restrict__ qkv_w, const float* __restrict__ proj_w,
                  unsigned short* __restrict__ wq, unsigned short* __restrict__ wp)
{
    const int t = blockIdx.x * 512 + threadIdx.x;
    if (t < 96 * 64) {
        const int lane = t & 63, g = t >> 6;
        const int l16 = lane & 15, lg = lane >> 4;
        const int ks = g & 3, wn = g >> 2;                 // wn = wave*3+nt
        const int ch = wn * 16 + l16;                      // qkv output channel
        const float s = (ch < 128) ? (SCALE_Q * LOG2E) : 1.0f;
        const float* p = qkv_w + (size_t)ch * 128 + ks * 32 + lg * 8;
        bf16x8 f;
#pragma unroll
        for (int j = 0; j < 8; ++j) f[j] = (short)f2bf(p[j] * s);
        *(bf16x8*)&wq[(size_t)t * 8] = f;
    } else if (t < 96 * 64 + 32 * 64) {
        const int t2 = t - 96 * 64;
        const int lane = t2 & 63, g = t2 >> 6;             // g = wave*4+ks
        const int l16 = lane & 15, lg = lane >> 4;
        const int ks = g & 3, wv = g >> 2;
        const float* p = proj_w + (size_t)(wv * 16 + l16) * 128 + ks * 32 + lg * 8;
        bf16x8 f;
#pragma unroll
        for (int j = 0; j < 8; ++j) f[j] = (short)f2bf(p[j]);
        *(bf16x8*)&wp[(size_t)t2 * 8] = f;
    }
}

__global__ __launch_bounds__(THREADS, 4)
void winattn_kernel(const float* __restrict__ x, const float* __restrict__ mask,
                    const unsigned short* __restrict__ wq, const unsigned short* __restrict__ wpr,
                    const float* __restrict__ qkv_b, const float* __restrict__ proj_b,
                    const float* __restrict__ bias_table, const int* __restrict__ rel_index,
                    float* __restrict__ out)
{
    __shared__ __align__(16) unsigned short pool[POOL_USHORTS];
    float* maskF = (float*)&pool[MS_OFF];

    const int tid  = threadIdx.x;
    const int wave = tid >> 6;
    const int lane = tid & 63;
    const int lg   = lane >> 4;
    const int l16  = lane & 15;
    const int h    = wave >> 1;      // head
    const int mh   = wave & 1;       // q-half (32 tokens)

    // ---------------- persistent per-block state (~22 VGPRs) ----------------
    unsigned biasP[2][4][2];
#pragma unroll
    for (int nt = 0; nt < 2; ++nt) {
        int qt = mh * 32 + nt * 16 + l16; if (qt > 48) qt = 48;
#pragma unroll
        for (int mt = 0; mt < 4; ++mt) {
#pragma unroll
            for (int w2 = 0; w2 < 2; ++w2) {
                float b[2];
#pragma unroll
                for (int r = 0; r < 2; ++r) {
                    int kt = mt * 16 + lg * 4 + w2 * 2 + r; if (kt > 48) kt = 48;
                    const int idx = rel_index[qt * 49 + kt];
                    b[r] = bias_table[idx * 4 + h] * LOG2E;
                }
                biasP[nt][mt][w2] = pack2bf(b[0], b[1]);
            }
        }
    }
    const float4 pb = *(const float4*)(proj_b + wave * 16 + lg * 4);

    const int win0 = blockIdx.x * WPB;

    // ---------------- prologue: zero qk+vt, stage window 0 ----------------
    {
        unsigned* p32 = (unsigned*)pool;
        for (int i = QK_OFF / 2 + tid; i < QK_OFF / 2 + (12936 + 9216) / 2; i += THREADS)
            p32[i] = 0;
    }
#pragma unroll
    for (int it = 0; it < 4; ++it) {
        const int e = it * 2048 + tid * 4;
        if (e < 6272) {
            float4 v = *(const float4*)(x + (size_t)win0 * 6272 + e);
            *(ushort4*)&pool[XA_OFF + (e >> 7) * XAP + (e & 127)] = cvt4(v);
        }
    }
    {
        const float* mp0 = mask + (size_t)(win0 & 1023) * 2401;
        for (int e = tid; e < 2401; e += THREADS)
            maskF[(e / 49) * MSP + (e % 49)] = mp0[e] * LOG2E;
    }
    __syncthreads();

    for (int w = 0; w < WPB; ++w) {
        const int win = win0 + w;
        const bool pf = (w + 1 < WPB);

        // -------- QKV GEMM, nt-outer (one 16-reg wB tile live at a time) --------
        {
            uintptr_t wqu = (uintptr_t)wq;
            asm volatile("" : "+s"(wqu));
            const unsigned short* wqx = (const unsigned short*)wqu;
#pragma unroll
            for (int nt = 0; nt < 3; ++nt) {
                bf16x8 wB[4];
#pragma unroll
                for (int ks = 0; ks < 4; ++ks)
                    wB[ks] = *(const bf16x8*)&wqx[(size_t)(((wave * 3 + nt) * 4 + ks) * 64 + lane) * 8];
                const int chB = wave * 48 + nt * 16;
                float4 qb4;
                if (chB < 256) {
                    qb4 = *(const float4*)(qkv_b + chB + lg * 4);
                    if (chB < 128) { qb4.x *= SCALE_Q * LOG2E; qb4.y *= SCALE_Q * LOG2E;
                                     qb4.z *= SCALE_Q * LOG2E; qb4.w *= SCALE_Q * LOG2E; }
                } else {
                    qb4.x = qkv_b[chB + l16];
                }
#pragma unroll
                for (int mt = 0; mt < 4; ++mt) {
                    bf16x8 xf[4];
#pragma unroll
                    for (int ks = 0; ks < 4; ++ks)
                        xf[ks] = *(const bf16x8*)&pool[XA_OFF + (mt * 16 + l16) * XAP + ks * 32 + lg * 8];
                    f32x4 acc = (f32x4){0.f, 0.f, 0.f, 0.f};
                    if (chB < 256) {
#pragma unroll
                        for (int ks = 0; ks < 4; ++ks)
                            acc = __builtin_amdgcn_mfma_f32_16x16x32_bf16(wB[ks], xf[ks], acc, 0, 0, 0);
                        const int tok = mt * 16 + l16;
                        if (tok < 49) {
                            float4 v; v.x = acc[0] + qb4.x; v.y = acc[1] + qb4.y;
                            v.z = acc[2] + qb4.z; v.w = acc[3] + qb4.w;
                            *(ushort4*)&pool[QK_OFF + tok * QKP + chB + lg * 4] = cvt4(v);
                        }
                    } else {
#pragma unroll
                        for (int ks = 0; ks < 4; ++ks)
                            acc = __builtin_amdgcn_mfma_f32_16x16x32_bf16(xf[ks], wB[ks], acc, 0, 0, 0);
                        const float vb = qb4.x;
                        float4 v; v.x = acc[0] + vb; v.y = acc[1] + vb;
                        v.z = acc[2] + vb; v.w = acc[3] + vb;
                        *(ushort4*)&pool[VT_OFF + (chB - 256 + l16) * VTP + mt * 16 + lg * 4] = cvt4(v);
                    }
                }
            }
        }
        __syncthreads();   // BAR1: q/k/v visible; xa free (consumed)

        // -------- attention: S' = K * Q^T (softmax over in-lane kt) --------
        bf16x8 ak[4];
#pragma unroll
        for (int mt = 0; mt < 4; ++mt)
            ak[mt] = *(const bf16x8*)&pool[QK_OFF + (mt * 16 + l16) * QKP + 128 + h * 32 + lg * 8];

        float inv[2];
        unsigned pk[2][4][2];
#pragma unroll
        for (int nt = 0; nt < 2; ++nt) {
            const bf16x8 bq = *(const bf16x8*)&pool[QK_OFF + (mh * 32 + nt * 16 + l16) * QKP + h * 32 + lg * 8];
            f32x4 S[4];
#pragma unroll
            for (int mt = 0; mt < 4; ++mt)
                S[mt] = __builtin_amdgcn_mfma_f32_16x16x32_bf16(ak[mt], bq, (f32x4){0.f,0.f,0.f,0.f}, 0, 0, 0);

            const int qt = mh * 32 + nt * 16 + l16;
            const bool qok = (qt < 49);
            const int qrow = qok ? qt : 48;
            float lv[4][4];
#pragma unroll
            for (int mt = 0; mt < 4; ++mt) {
                const float4 mm = *(const float4*)&maskF[qrow * MSP + mt * 16 + lg * 4];
                const unsigned b0 = biasP[nt][mt][0], b1 = biasP[nt][mt][1];
                const float bb0 = __uint_as_float(b0 << 16);
                const float bb1 = __uint_as_float(b0 & 0xffff0000u);
                const float bb2 = __uint_as_float(b1 << 16);
                const float bb3 = __uint_as_float(b1 & 0xffff0000u);
                const int kt0 = mt * 16 + lg * 4;
                lv[mt][0] = (qok && kt0 + 0 < 49) ? (S[mt][0] + bb0 + mm.x) : -1e30f;
                lv[mt][1] = (qok && kt0 + 1 < 49) ? (S[mt][1] + bb1 + mm.y) : -1e30f;
                lv[mt][2] = (qok && kt0 + 2 < 49) ? (S[mt][2] + bb2 + mm.z) : -1e30f;
                lv[mt][3] = (qok && kt0 + 3 < 49) ? (S[mt][3] + bb3 + mm.w) : -1e30f;
            }
            float mx = lv[0][0];
#pragma unroll
            for (int mt = 0; mt < 4; ++mt)
#pragma unroll
                for (int r = 0; r < 4; ++r) mx = fmaxf(mx, lv[mt][r]);
            mx = fmaxf(mx, __shfl_xor(mx, 16));
            mx = fmaxf(mx, __shfl_xor(mx, 32));
            float sum = 0.f;
#pragma unroll
            for (int mt = 0; mt < 4; ++mt)
#pragma unroll
                for (int r = 0; r < 4; ++r) {
                    const float p = exp2f(lv[mt][r] - mx);
                    lv[mt][r] = p;
                    sum += p;
                }
            sum += __shfl_xor(sum, 16);
            sum += __shfl_xor(sum, 32);
            inv[nt] = 1.0f / sum;
#pragma unroll
            for (int mt = 0; mt < 4; ++mt) {
                pk[nt][mt][0] = pack2bf(lv[mt][0], lv[mt][1]);
                pk[nt][mt][1] = pack2bf(lv[mt][2], lv[mt][3]);
            }
        }

        // -------- PV: O' = V^T * P^T (per-wave LDS P round-trips) --------
        f32x4 O[2][2];   // [dim-tile][tok-tile]
#pragma unroll
        for (int i = 0; i < 2; ++i)
#pragma unroll
            for (int j = 0; j < 2; ++j) O[i][j] = (f32x4){0.f, 0.f, 0.f, 0.f};
        const int psb = PS_OFF + wave * 16 * PSP;
#pragma unroll
        for (int kh = 0; kh < 2; ++kh) {
            bf16x8 bv[2];
#pragma unroll
            for (int i = 0; i < 2; ++i)
                bv[i] = *(const bf16x8*)&pool[VT_OFF + (h * 32 + i * 16 + l16) * VTP + kh * 32 + lg * 8];
#pragma unroll
            for (int j = 0; j < 2; ++j) {
                uint2 t0, t1;
                t0.x = pk[j][2 * kh + 0][0]; t0.y = pk[j][2 * kh + 0][1];
                t1.x = pk[j][2 * kh + 1][0]; t1.y = pk[j][2 * kh + 1][1];
                *(uint2*)&pool[psb + l16 * PSP + lg * 4]      = t0;
                *(uint2*)&pool[psb + l16 * PSP + 16 + lg * 4] = t1;
                asm volatile("s_waitcnt lgkmcnt(0)" ::: "memory");
                __builtin_amdgcn_sched_barrier(0);
                const bf16x8 pa = *(const bf16x8*)&pool[psb + l16 * PSP + lg * 8];
#pragma unroll
                for (int i = 0; i < 2; ++i)
                    O[i][j] = __builtin_amdgcn_mfma_f32_16x16x32_bf16(bv[i], pa, O[i][j], 0, 0, 0);
            }
        }
        // attn-out -> xa (row write along dims), fold 1/sum
#pragma unroll
        for (int j = 0; j < 2; ++j) {
            const int tok = mh * 32 + j * 16 + l16;
            if (tok < 49) {
#pragma unroll
                for (int i = 0; i < 2; ++i) {
                    float4 v;
                    v.x = O[i][j][0] * inv[j]; v.y = O[i][j][1] * inv[j];
                    v.z = O[i][j][2] * inv[j]; v.w = O[i][j][3] * inv[j];
                    *(ushort4*)&pool[XA_OFF + tok * XAP + h * 32 + i * 16 + lg * 4] = cvt4(v);
                }
            }
        }
        __syncthreads();   // BAR2: attn-out visible; maskF free

        // stage next window's mask (global -> LDS; latency covered by 2nd block)
        if (pf) {
            const float* mp1 = mask + (size_t)((win + 1) & 1023) * 2401;
            for (int e = tid; e < 2401; e += THREADS)
                maskF[(e / 49) * MSP + (e % 49)] = mp1[e] * LOG2E;
        }

        // -------- proj: out^T = proj_w * aout^T (coalesced float4 store) --------
        bf16x8 wp_[4];
        {
            uintptr_t wpu = (uintptr_t)wpr;
            asm volatile("" : "+s"(wpu));
            const unsigned short* wpx = (const unsigned short*)wpu;
#pragma unroll
            for (int ks = 0; ks < 4; ++ks)
                wp_[ks] = *(const bf16x8*)&wpx[(size_t)((wave * 4 + ks) * 64 + lane) * 8];
        }
#pragma unroll
        for (int nt4 = 0; nt4 < 4; ++nt4) {
            f32x4 pc = (f32x4){0.f, 0.f, 0.f, 0.f};
#pragma unroll
            for (int ks = 0; ks < 4; ++ks) {
                const bf16x8 bfr = *(const bf16x8*)&pool[XA_OFF + (nt4 * 16 + l16) * XAP + ks * 32 + lg * 8];
                pc = __builtin_amdgcn_mfma_f32_16x16x32_bf16(wp_[ks], bfr, pc, 0, 0, 0);
            }
            const int tok = nt4 * 16 + l16;
            if (tok < 49) {
                float4 o;
                o.x = pc[0] + pb.x; o.y = pc[1] + pb.y;
                o.z = pc[2] + pb.z; o.w = pc[3] + pb.w;
                *(float4*)(out + ((size_t)win * 49 + tok) * 128 + wave * 16 + lg * 4) = o;
            }
        }
        __syncthreads();   // BAR3: proj's xa reads done

        // stage next window's x (global -> cvt -> LDS; latency covered by 2nd block)
        if (pf) {
            const float* xp1 = x + (size_t)(win + 1) * 6272;
#pragma unroll
            for (int it = 0; it < 4; ++it) {
                const int e = it * 2048 + tid * 4;
                if (e < 6272) {
                    float4 v = *(const float4*)(xp1 + e);
                    *(ushort4*)&pool[XA_OFF + (e >> 7) * XAP + (e & 127)] = cvt4(v);
                }
            }
        }
        __syncthreads();   // BAR4: next window's x staged
    }
}

extern "C" void kernel_launch(void* const* d_in, const int* in_sizes, int n_in,
                              void* d_out, int out_size, void* d_ws, size_t ws_size,
                              hipStream_t stream) {
    const float* x          = (const float*)d_in[0];
    const float* mask       = (const float*)d_in[1];
    const float* qkv_w      = (const float*)d_in[2];
    const float* qkv_b      = (const float*)d_in[3];
    const float* proj_w     = (const float*)d_in[4];
    const float* proj_b     = (const float*)d_in[5];
    const float* bias_table = (const float*)d_in[6];
    const int*   rel_index  = (const int*)d_in[7];
    float* out = (float*)d_out;
    (void)in_sizes; (void)n_in; (void)ws_size; (void)out_size;

    unsigned short* wq = (unsigned short*)d_ws;
    unsigned short* wp = wq + WQ_USHORTS;

    prep_weights<<<dim3(16), dim3(512), 0, stream>>>(qkv_w, proj_w, wq, wp);
    winattn_kernel<<<dim3(NBLK), dim3(THREADS), 0, stream>>>(
        x, mask, wq, wp, qkv_b, proj_b, bias_table, rel_index, out);
}

// Round 7
// 416.218 us; speedup vs baseline: 2.9663x; 1.0907x over previous
//
#include <hip/hip_runtime.h>
#include <hip/hip_bf16.h>

#define THREADS 512
#define WPB 8
#define NWIN 16384
#define NBLK (NWIN / WPB)

typedef short bf16x8 __attribute__((ext_vector_type(8)));
typedef float f32x4 __attribute__((ext_vector_type(4)));

// ---- LDS pool (ushort units). Deliberate over-reads of padded MFMA rows land
// in the next region (finite bf16 values, results discarded) — all in-pool. ----
#define XAP 136   // xa0/xa1: [49][136] bf16 (x staging / attn-out, ping-pong)
#define QKP 264   // qk: [49][264] bf16  (cols 0..255 = q|k channels)
#define VTP 72    // vt: [128][72] bf16  (rows = dims, cols = tokens)
#define PSP 40    // ps: per-wave [16][40] bf16 P staging

#define XA0_OFF 0
#define XA1_OFF 6664
#define QK_OFF  13328
#define VT_OFF  26264
#define PS_OFF  35480
#define POOL_USHORTS 40600      // 81,200 bytes -> 81,408 alloc -> 2 blocks/CU

#define LOG2E 1.4426950408889634f
#define SCALE_Q 0.17677669529663689f   // 32^-0.5

// ws layout: comb[1024][4][49][52] f32, then wq, then wp fragments
#define COMB_FLOATS (1024 * 4 * 49 * 52)
#define COMB_BYTES  ((size_t)COMB_FLOATS * 4)
#define WQ_USHORTS (96 * 64 * 8)
#define WP_USHORTS (32 * 64 * 8)

static __device__ __forceinline__ unsigned short f2bf(float x) {
    union { __hip_bfloat16 b; unsigned short u; } c;
    c.b = __float2bfloat16(x);
    return c.u;
}
static __device__ __forceinline__ unsigned pack2bf(float lo, float hi) {
    return (unsigned)f2bf(lo) | ((unsigned)f2bf(hi) << 16);
}
static __device__ __forceinline__ ushort4 cvt4(float4 v) {
    ushort4 u; u.x = f2bf(v.x); u.y = f2bf(v.y); u.z = f2bf(v.z); u.w = f2bf(v.w);
    return u;
}

// ---------------- prep: fp32 weights -> pre-swizzled bf16 fragments ----------------
__global__ __launch_bounds__(512)
void prep_weights(const float* __restrict__ qkv_w, const float* __restrict__ proj_w,
                  unsigned short* __restrict__ wq, unsigned short* __restrict__ wp)
{
    const int t = blockIdx.x * 512 + threadIdx.x;
    if (t < 96 * 64) {
        const int lane = t & 63, g = t >> 6;
        const int l16 = lane & 15, lg = lane >> 4;
        const int ks = g & 3, wn = g >> 2;                 // wn = wave*3+nt
        const int ch = wn * 16 + l16;                      // qkv output channel
        const float s = (ch < 128) ? (SCALE_Q * LOG2E) : 1.0f;
        const float* p = qkv_w + (size_t)ch * 128 + ks * 32 + lg * 8;
        bf16x8 f;
#pragma unroll
        for (int j = 0; j < 8; ++j) f[j] = (short)f2bf(p[j] * s);
        *(bf16x8*)&wq[(size_t)t * 8] = f;
    } else if (t < 96 * 64 + 32 * 64) {
        const int t2 = t - 96 * 64;
        const int lane = t2 & 63, g = t2 >> 6;             // g = wave*4+ks
        const int l16 = lane & 15, lg = lane >> 4;
        const int ks = g & 3, wv = g >> 2;
        const float* p = proj_w + (size_t)(wv * 16 + l16) * 128 + ks * 32 + lg * 8;
        bf16x8 f;
#pragma unroll
        for (int j = 0; j < 8; ++j) f[j] = (short)f2bf(p[j]);
        *(bf16x8*)&wp[(size_t)t2 * 8] = f;
    }
}

// ---------------- prep: comb[wi][h][qt][52] = (mask + rel_bias) * log2e ----------------
__global__ __launch_bounds__(512)
void prep_comb(const float* __restrict__ mask, const float* __restrict__ bias_table,
               const int* __restrict__ rel_index, float* __restrict__ comb)
{
    const unsigned t = blockIdx.x * 512 + threadIdx.x;
    if (t >= 1024u * 4u * 49u * 49u) return;
    const unsigned wi = t / 9604u;            // 4*49*49
    const unsigned r1 = t - wi * 9604u;
    const unsigned h  = r1 / 2401u;
    const unsigned r2 = r1 - h * 2401u;       // qt*49 + kt
    const unsigned qt = r2 / 49u;
    const unsigned kt = r2 - qt * 49u;
    const float m = mask[wi * 2401u + r2];
    const float b = bias_table[rel_index[r2] * 4 + h];
    comb[(((size_t)wi * 4u + h) * 49u + qt) * 52u + kt] = (m + b) * LOG2E;
}

__global__ __launch_bounds__(THREADS, 4)
void winattn_kernel(const float* __restrict__ x, const float* __restrict__ comb,
                    const unsigned short* __restrict__ wq, const unsigned short* __restrict__ wpr,
                    const float* __restrict__ qkv_b, const float* __restrict__ proj_b,
                    float* __restrict__ out)
{
    __shared__ __align__(16) unsigned short pool[POOL_USHORTS];

    const int tid  = threadIdx.x;
    const int wave = tid >> 6;
    const int lane = tid & 63;
    const int lg   = lane >> 4;
    const int l16  = lane & 15;
    const int h    = wave >> 1;      // head
    const int mh   = wave & 1;       // q-half (32 tokens)

    const float4 pb = *(const float4*)(proj_b + wave * 16 + lg * 4);

    const int win0 = blockIdx.x * WPB;

    // ---------------- prologue: zero qk+vt, stage window 0 into xa0 ----------------
    {
        unsigned* p32 = (unsigned*)pool;
        for (int i = QK_OFF / 2 + tid; i < (QK_OFF + 12936 + 9216) / 2; i += THREADS)
            p32[i] = 0;
    }
#pragma unroll
    for (int it = 0; it < 4; ++it) {
        const int e = it * 2048 + tid * 4;
        if (e < 6272) {
            float4 v = *(const float4*)(x + (size_t)win0 * 6272 + e);
            *(ushort4*)&pool[XA0_OFF + (e >> 7) * XAP + (e & 127)] = cvt4(v);
        }
    }
    __syncthreads();

    for (int w = 0; w < WPB; ++w) {
        const int win = win0 + w;
        const bool pf = (w + 1 < WPB);
        const int xaC = (w & 1) ? XA1_OFF : XA0_OFF;   // current window's x / attn-out
        const int xaN = (w & 1) ? XA0_OFF : XA1_OFF;   // next window's x

        // -------- stage next window's x into the free buffer (no barrier needed:
        //          xaN's last reader was proj of w-1, done at BAR3) --------
        if (pf) {
            const float* xp1 = x + (size_t)(win + 1) * 6272;
#pragma unroll
            for (int it = 0; it < 4; ++it) {
                const int e = it * 2048 + tid * 4;
                if (e < 6272) {
                    float4 v = *(const float4*)(xp1 + e);
                    *(ushort4*)&pool[xaN + (e >> 7) * XAP + (e & 127)] = cvt4(v);
                }
            }
        }

        // -------- QKV GEMM, nt-outer (one 16-reg wB tile live at a time) --------
        {
            uintptr_t wqu = (uintptr_t)wq;
            asm volatile("" : "+s"(wqu));
            const unsigned short* wqx = (const unsigned short*)wqu;
#pragma unroll
            for (int nt = 0; nt < 3; ++nt) {
                bf16x8 wB[4];
#pragma unroll
                for (int ks = 0; ks < 4; ++ks)
                    wB[ks] = *(const bf16x8*)&wqx[(size_t)(((wave * 3 + nt) * 4 + ks) * 64 + lane) * 8];
                const int chB = wave * 48 + nt * 16;
                float4 qb4;
                if (chB < 256) {
                    qb4 = *(const float4*)(qkv_b + chB + lg * 4);
                    if (chB < 128) { qb4.x *= SCALE_Q * LOG2E; qb4.y *= SCALE_Q * LOG2E;
                                     qb4.z *= SCALE_Q * LOG2E; qb4.w *= SCALE_Q * LOG2E; }
                } else {
                    qb4.x = qkv_b[chB + l16];
                }
#pragma unroll
                for (int mt = 0; mt < 4; ++mt) {
                    bf16x8 xf[4];
#pragma unroll
                    for (int ks = 0; ks < 4; ++ks)
                        xf[ks] = *(const bf16x8*)&pool[xaC + (mt * 16 + l16) * XAP + ks * 32 + lg * 8];
                    f32x4 acc = (f32x4){0.f, 0.f, 0.f, 0.f};
                    if (chB < 256) {
#pragma unroll
                        for (int ks = 0; ks < 4; ++ks)
                            acc = __builtin_amdgcn_mfma_f32_16x16x32_bf16(wB[ks], xf[ks], acc, 0, 0, 0);
                        const int tok = mt * 16 + l16;
                        if (tok < 49) {
                            float4 v; v.x = acc[0] + qb4.x; v.y = acc[1] + qb4.y;
                            v.z = acc[2] + qb4.z; v.w = acc[3] + qb4.w;
                            *(ushort4*)&pool[QK_OFF + tok * QKP + chB + lg * 4] = cvt4(v);
                        }
                    } else {
#pragma unroll
                        for (int ks = 0; ks < 4; ++ks)
                            acc = __builtin_amdgcn_mfma_f32_16x16x32_bf16(xf[ks], wB[ks], acc, 0, 0, 0);
                        const float vb = qb4.x;
                        float4 v; v.x = acc[0] + vb; v.y = acc[1] + vb;
                        v.z = acc[2] + vb; v.w = acc[3] + vb;
                        *(ushort4*)&pool[VT_OFF + (chB - 256 + l16) * VTP + mt * 16 + lg * 4] = cvt4(v);
                    }
                }
            }
        }
        __syncthreads();   // BAR1: q/k/v visible

        // -------- attention: S' = K * Q^T; logits = S + comb (fp32 table) --------
        const float* combW = comb + ((size_t)((win & 1023) * 4 + h)) * (49 * 52);
        float inv[2];
        unsigned pk[2][4][2];
#pragma unroll
        for (int nt = 0; nt < 2; ++nt) {
            const int qt = mh * 32 + nt * 16 + l16;
            const int qrow = (qt > 48) ? 48 : qt;
            const float* crow = combW + qrow * 52;
            const float4 c0 = *(const float4*)(crow + lg * 4);
            const float4 c1 = *(const float4*)(crow + 16 + lg * 4);
            const float4 c2 = *(const float4*)(crow + 32 + lg * 4);
            const float  c3 = crow[48];
            const bf16x8 bq = *(const bf16x8*)&pool[QK_OFF + qt * QKP + h * 32 + lg * 8];
            f32x4 S[4];
#pragma unroll
            for (int mt = 0; mt < 4; ++mt) {
                const bf16x8 ak = *(const bf16x8*)&pool[QK_OFF + (mt * 16 + l16) * QKP + 128 + h * 32 + lg * 8];
                S[mt] = __builtin_amdgcn_mfma_f32_16x16x32_bf16(ak, bq, (f32x4){0.f,0.f,0.f,0.f}, 0, 0, 0);
            }
            float lv[12];
            lv[0] = S[0][0] + c0.x; lv[1] = S[0][1] + c0.y;
            lv[2] = S[0][2] + c0.z; lv[3] = S[0][3] + c0.w;
            lv[4] = S[1][0] + c1.x; lv[5] = S[1][1] + c1.y;
            lv[6] = S[1][2] + c1.z; lv[7] = S[1][3] + c1.w;
            lv[8] = S[2][0] + c2.x; lv[9] = S[2][1] + c2.y;
            lv[10] = S[2][2] + c2.z; lv[11] = S[2][3] + c2.w;
            const float lv3 = (lg == 0) ? (S[3][0] + c3) : -1e30f;   // kt=48; kt>48 masked

            float mx = lv3;
#pragma unroll
            for (int i = 0; i < 12; ++i) mx = fmaxf(mx, lv[i]);
            mx = fmaxf(mx, __shfl_xor(mx, 16));
            mx = fmaxf(mx, __shfl_xor(mx, 32));
            float sum = 0.f;
#pragma unroll
            for (int i = 0; i < 12; ++i) {
                const float p = exp2f(lv[i] - mx);
                lv[i] = p;
                sum += p;
            }
            const float p3 = exp2f(lv3 - mx);
            sum += p3;
            sum += __shfl_xor(sum, 16);
            sum += __shfl_xor(sum, 32);
            inv[nt] = 1.0f / sum;
            pk[nt][0][0] = pack2bf(lv[0], lv[1]);  pk[nt][0][1] = pack2bf(lv[2], lv[3]);
            pk[nt][1][0] = pack2bf(lv[4], lv[5]);  pk[nt][1][1] = pack2bf(lv[6], lv[7]);
            pk[nt][2][0] = pack2bf(lv[8], lv[9]);  pk[nt][2][1] = pack2bf(lv[10], lv[11]);
            pk[nt][3][0] = pack2bf(p3, 0.f);       pk[nt][3][1] = 0u;
        }

        // -------- PV: O' = V^T * P^T (per-wave LDS P round-trips) --------
        f32x4 O[2][2];   // [dim-tile][tok-tile]
#pragma unroll
        for (int i = 0; i < 2; ++i)
#pragma unroll
            for (int j = 0; j < 2; ++j) O[i][j] = (f32x4){0.f, 0.f, 0.f, 0.f};
        const int psb = PS_OFF + wave * 16 * PSP;
#pragma unroll
        for (int kh = 0; kh < 2; ++kh) {
            bf16x8 bv[2];
#pragma unroll
            for (int i = 0; i < 2; ++i)
                bv[i] = *(const bf16x8*)&pool[VT_OFF + (h * 32 + i * 16 + l16) * VTP + kh * 32 + lg * 8];
#pragma unroll
            for (int j = 0; j < 2; ++j) {
                uint2 t0, t1;
                t0.x = pk[j][2 * kh + 0][0]; t0.y = pk[j][2 * kh + 0][1];
                t1.x = pk[j][2 * kh + 1][0]; t1.y = pk[j][2 * kh + 1][1];
                *(uint2*)&pool[psb + l16 * PSP + lg * 4]      = t0;
                *(uint2*)&pool[psb + l16 * PSP + 16 + lg * 4] = t1;
                asm volatile("s_waitcnt lgkmcnt(0)" ::: "memory");
                __builtin_amdgcn_sched_barrier(0);
                const bf16x8 pa = *(const bf16x8*)&pool[psb + l16 * PSP + lg * 8];
#pragma unroll
                for (int i = 0; i < 2; ++i)
                    O[i][j] = __builtin_amdgcn_mfma_f32_16x16x32_bf16(bv[i], pa, O[i][j], 0, 0, 0);
            }
        }
        // attn-out -> xa[cur] (row write along dims), fold 1/sum
#pragma unroll
        for (int j = 0; j < 2; ++j) {
            const int tok = mh * 32 + j * 16 + l16;
            if (tok < 49) {
#pragma unroll
                for (int i = 0; i < 2; ++i) {
                    float4 v;
                    v.x = O[i][j][0] * inv[j]; v.y = O[i][j][1] * inv[j];
                    v.z = O[i][j][2] * inv[j]; v.w = O[i][j][3] * inv[j];
                    *(ushort4*)&pool[xaC + tok * XAP + h * 32 + i * 16 + lg * 4] = cvt4(v);
                }
            }
        }
        __syncthreads();   // BAR2: attn-out visible

        // -------- proj: out^T = proj_w * aout^T (coalesced float4 store) --------
        bf16x8 wp_[4];
        {
            uintptr_t wpu = (uintptr_t)wpr;
            asm volatile("" : "+s"(wpu));
            const unsigned short* wpx = (const unsigned short*)wpu;
#pragma unroll
            for (int ks = 0; ks < 4; ++ks)
                wp_[ks] = *(const bf16x8*)&wpx[(size_t)((wave * 4 + ks) * 64 + lane) * 8];
        }
#pragma unroll
        for (int nt4 = 0; nt4 < 4; ++nt4) {
            f32x4 pc = (f32x4){0.f, 0.f, 0.f, 0.f};
#pragma unroll
            for (int ks = 0; ks < 4; ++ks) {
                const bf16x8 bfr = *(const bf16x8*)&pool[xaC + (nt4 * 16 + l16) * XAP + ks * 32 + lg * 8];
                pc = __builtin_amdgcn_mfma_f32_16x16x32_bf16(wp_[ks], bfr, pc, 0, 0, 0);
            }
            const int tok = nt4 * 16 + l16;
            if (tok < 49) {
                float4 o;
                o.x = pc[0] + pb.x; o.y = pc[1] + pb.y;
                o.z = pc[2] + pb.z; o.w = pc[3] + pb.w;
                *(float4*)(out + ((size_t)win * 49 + tok) * 128 + wave * 16 + lg * 4) = o;
            }
        }
        __syncthreads();   // BAR3: proj reads done; next QKV + next staging safe
    }
}

extern "C" void kernel_launch(void* const* d_in, const int* in_sizes, int n_in,
                              void* d_out, int out_size, void* d_ws, size_t ws_size,
                              hipStream_t stream) {
    const float* x          = (const float*)d_in[0];
    const float* mask       = (const float*)d_in[1];
    const float* qkv_w      = (const float*)d_in[2];
    const float* qkv_b      = (const float*)d_in[3];
    const float* proj_w     = (const float*)d_in[4];
    const float* proj_b     = (const float*)d_in[5];
    const float* bias_table = (const float*)d_in[6];
    const int*   rel_index  = (const int*)d_in[7];
    float* out = (float*)d_out;
    (void)in_sizes; (void)n_in; (void)ws_size; (void)out_size;

    float* comb = (float*)d_ws;
    unsigned short* wq = (unsigned short*)((char*)d_ws + COMB_BYTES);
    unsigned short* wp = wq + WQ_USHORTS;

    prep_weights<<<dim3(16), dim3(512), 0, stream>>>(qkv_w, proj_w, wq, wp);
    prep_comb<<<dim3(19208), dim3(512), 0, stream>>>(mask, bias_table, rel_index, comb);
    winattn_kernel<<<dim3(NBLK), dim3(THREADS), 0, stream>>>(
        x, comb, wq, wp, qkv_b, proj_b, out);
}